// Round 4
// baseline (205.155 us; speedup 1.0000x reference)
//
#include <hip/hip_runtime.h>
#include <hip/hip_bf16.h>
#include <stdint.h>

#define S_LEN 2048
#define NH 16
#define NB_DELTA (2*S_LEN-1)   // 4095
#define LOG2E 1.4426950408889634f

typedef __attribute__((ext_vector_type(8))) __bf16 bf16x8;
typedef __attribute__((ext_vector_type(4))) float f32x4;

__device__ __forceinline__ unsigned short f2bf(float f){   // RNE
    union { float f; unsigned int u; } v; v.f = f;
    unsigned int u = v.u;
    return (unsigned short)((u + 0x7FFFu + ((u >> 16) & 1u)) >> 16);
}
__device__ __forceinline__ float bf2f(unsigned short u){
    union { unsigned int u; float f; } v; v.u = ((unsigned int)u) << 16;
    return v.f;
}
__device__ __forceinline__ unsigned int pkbf(float a, float b){   // HW packed cvt (RNE)
    __hip_bfloat162 h = __float22bfloat162_rn(float2{a, b});
    unsigned int u;
    __builtin_memcpy(&u, &h, 4);
    return u;
}
#if __has_builtin(__builtin_amdgcn_exp2f)
__device__ __forceinline__ float fexp2(float x){ return __builtin_amdgcn_exp2f(x); }
#else
__device__ __forceinline__ float fexp2(float x){ return __expf(x * 0.69314718056f); }
#endif

// async global->LDS, 16B per lane; LDS dest = wave-uniform base + lane*16
__device__ __forceinline__ void gload16(const void* g, void* l){
    __builtin_amdgcn_global_load_lds(
        (const __attribute__((address_space(1))) void*)(uintptr_t)g,
        (__attribute__((address_space(3))) void*)(uintptr_t)l, 16, 0, 0);
}

// ---------------- fused prep: z<4 -> transpose+cast W[z]; z==4 -> hs cast + bias table
// biasT is PRE-SCALED: (bias - 16) * log2e  (exp2-softmax form; the -16 cancels in softmax)
__global__ __launch_bounds__(256) void prep_kernel(
    const float* __restrict__ hs, unsigned short* __restrict__ hsb,
    const float* __restrict__ W0, const float* __restrict__ W1,
    const float* __restrict__ W2, const float* __restrict__ W3,
    unsigned short* __restrict__ D0, unsigned short* __restrict__ D1,
    unsigned short* __restrict__ D2, unsigned short* __restrict__ D3,
    const float* __restrict__ rel_bias, float* __restrict__ biasT){
    if (blockIdx.z == 4) {
        int bi = blockIdx.y * 32 + blockIdx.x;   // 0..1023
        for (int it = 0; it < 4; it++) {
            int i = bi * 4096 + it * 1024 + threadIdx.x * 4;
            float4 f = *(const float4*)(hs + i);
            ushort4 o;
            o.x = f2bf(f.x); o.y = f2bf(f.y); o.z = f2bf(f.z); o.w = f2bf(f.w);
            *(ushort4*)(hsb + i) = o;
        }
        if (bi < 16) {
            int t = bi * 256 + threadIdx.x;
            if (t < NB_DELTA) {
                int delta = t - (S_LEN - 1);          // j - i
                int bucket = (delta > 0) ? 16 : 0;
                int a = delta < 0 ? -delta : delta;
                int b;
                if (a < 8) b = a;
                else {
                    int bl = 33 - __builtin_clz(a * a);   // 8 + floor(2*log2(a/8)), exact
                    b = bl < 15 ? bl : 15;
                }
                bucket += b;
                for (int h = 0; h < NH; h++)
                    biasT[h * NB_DELTA + t] = (rel_bias[bucket * NH + h] - 16.f) * LOG2E;
            }
        }
        return;
    }
    const float* src; unsigned short* dst;
    switch (blockIdx.z) {
        case 0: src = W0; dst = D0; break;
        case 1: src = W1; dst = D1; break;
        case 2: src = W2; dst = D2; break;
        default: src = W3; dst = D3; break;
    }
    __shared__ float tile[32][33];
    int bx = blockIdx.x, by = blockIdx.y;
    int tx = threadIdx.x & 31, ty = threadIdx.x >> 5;
    for (int i = 0; i < 4; i++)
        tile[ty + 8*i][tx] = src[(size_t)(by*32 + ty + 8*i) * 1024 + bx*32 + tx];
    __syncthreads();
    for (int i = 0; i < 4; i++)
        dst[(size_t)(bx*32 + ty + 8*i) * 1024 + by*32 + tx] = f2bf(tile[tx][ty + 8*i]);
}

// ---------------- bf16 MFMA GEMM, BK=64, async staging, XOR-granule-swizzled LDS.
// MODE 0: fp32 row-major into C0.
// MODE 1: bf16 row-major into C1 for cols<2048 (Q block pre-scaled by log2e);
//         cols>=2048 (the V block) are written TRANSPOSED into Vt[b*1024+v][s].
template<int MODE, int BM>
__global__ __launch_bounds__(256) void gemm_bt_kernel(const unsigned short* __restrict__ A,
                                                      const unsigned short* __restrict__ BT,
                                                      float* __restrict__ C0,
                                                      unsigned short* __restrict__ C1,
                                                      unsigned short* __restrict__ Vt,
                                                      int Kdim, int ldc){
    constexpr int IT = BM / 32;     // m-tiles per wave
    __shared__ __align__(16) unsigned short As[BM * 64];
    __shared__ __align__(16) unsigned short Bs[128 * 64];
    const int t = threadIdx.x;
    const int wave = t >> 6, lane = t & 63;
    const int quad = lane >> 4, l16 = lane & 15;
    const int wm = (wave >> 1) * (BM / 2), wn = (wave & 1) * 64;
    const size_t row0 = (size_t)blockIdx.y * BM, col0 = (size_t)blockIdx.x * 128;

    const int srow8 = lane >> 3;                 // 0..7: row within the wave's 8-row group
    const int gg = (lane & 7) ^ srow8;           // fetch-side granule remap
    const unsigned short* gA = A  + (row0 + wave * 8 + srow8) * (size_t)Kdim + gg * 8;
    const unsigned short* gB = BT + (col0 + wave * 8 + srow8) * (size_t)Kdim + gg * 8;

    f32x4 acc[IT][4] = {};

    for (int kt = 0; kt < Kdim; kt += 64) {
        for (int p = 0; p < BM / 32; p++)
            gload16(gA + (size_t)(p * 32) * Kdim + kt, &As[(p * 32 + wave * 8) * 64]);
        for (int p = 0; p < 4; p++)
            gload16(gB + (size_t)(p * 32) * Kdim + kt, &Bs[(p * 32 + wave * 8) * 64]);
        __syncthreads();
        bf16x8 a[2][IT], b[2][4];
        for (int ks = 0; ks < 2; ks++) {
            for (int i = 0; i < IT; i++)
                a[ks][i] = *(const bf16x8*)(&As[(wm + i*16 + l16) * 64 + (((ks*4 + quad) ^ (l16 & 7)) * 8)]);
            for (int j = 0; j < 4; j++)
                b[ks][j] = *(const bf16x8*)(&Bs[(wn + j*16 + l16) * 64 + (((ks*4 + quad) ^ (l16 & 7)) * 8)]);
        }
        for (int ks = 0; ks < 2; ks++)
            for (int i = 0; i < IT; i++)
                for (int j = 0; j < 4; j++)
                    acc[i][j] = __builtin_amdgcn_mfma_f32_16x16x32_bf16(a[ks][i], b[ks][j], acc[i][j], 0, 0, 0);
        __syncthreads();
    }
    // C/D layout: col = lane&15, row = quad*4 + reg
    for (int i = 0; i < IT; i++)
        for (int j = 0; j < 4; j++) {
            size_t r0 = row0 + wm + i*16 + quad*4;
            size_t c  = col0 + wn + j*16 + l16;
            if (MODE == 0) {
                for (int r = 0; r < 4; r++)
                    C0[(r0 + r) * ldc + c] = acc[i][j][r];
            } else if (c < 2048) {
                float qs = (c < 1024) ? LOG2E : 1.0f;   // pre-scale Q for exp2 softmax
                for (int r = 0; r < 4; r++)
                    C1[(r0 + r) * ldc + c] = f2bf(acc[i][j][r] * qs);
            } else {
                // V block: write transposed. rows r0..r0+3 are 4 consecutive s -> one 8B store.
                size_t bb = r0 >> 11, s = r0 & 2047;
                ushort4 o;
                o.x = f2bf(acc[i][j][0]); o.y = f2bf(acc[i][j][1]);
                o.z = f2bf(acc[i][j][2]); o.w = f2bf(acc[i][j][3]);
                *(ushort4*)(Vt + ((bb << 10) + (c - 2048)) * 2048 + s) = o;
            }
        }
}

// ---------------- MFMA flash attention v14:
// NEW vs v13: 4 blocks/CU (grid 1024, q-tile 128, wave owns 16 q rows) ->
// 32 waves/CU theoretical occupancy (2x TLP); chunked XCD swizzle so the 16
// qt-blocks sharing one (h,b,ck) K/V panel land on a single XCD (L2 reuse).
// Keeps: double-buffered K/V prefetch, bias as MFMA C-init, in-register P via
// permlane32/16_swap, row sums via ones-row MFMA.
__global__ __launch_bounds__(512, 8) void flash14_kernel(
    const unsigned short* __restrict__ qkv,
    const unsigned short* __restrict__ vt,
    const float* __restrict__ biasT,      // pre-scaled (x-16)*log2e
    unsigned short* __restrict__ ctxpb,   // [2][4096][1024] bf16 unnormalized
    float* __restrict__ rsbuf)            // [2][4096][16]  fp32 row sums
{
    // chunked XCD swizzle: physical lin -> logical id; the 16 blocks sharing
    // (h,b,ck) get identical lin%8 -> same XCD -> K/V panel fetched once/XCD.
    const int lin  = blockIdx.x;
    const int logi = (lin & 7) * 128 + (lin >> 3);
    const int qt = logi & 15, h = (logi >> 4) & 15;
    const int zz = logi >> 8;
    const int b = zz >> 1, ck = zz & 1;
    const int kt0 = ck << 10;
    const int t = threadIdx.x;
    const int w = t >> 6, lane = t & 63, quad = lane >> 4, l16 = lane & 15;
    const int q0 = qt * 128;

    __shared__ __align__(16) unsigned short Ks[2][64 * 64];   // [token j][dim], swizzled
    __shared__ __align__(16) unsigned short Vs[2][64 * 64];   // [dim d][token], swizzled
    __shared__ float bias_b[1152];                            // all deltas this block touches

    // bias table: delta range [kt0-q0-127, kt0-q0+1023] -> 1151 entries
    {
        const float* bsrc = biasT + h * NB_DELTA + (kt0 - q0 + 1920);   // 2047-127 = 1920
        for (int u = t; u < 1152; u += 512) bias_b[u] = bsrc[u];
    }
    const int srow8 = lane >> 3;
    const int gg = (lane & 7) ^ srow8;           // fetch-side granule remap
    const int swz = (l16 & 7) * 8;
    const unsigned short* kbase = qkv + (size_t)(b * S_LEN + w * 8 + srow8) * 3072 + 1024 + h * 64 + gg * 8;
    const unsigned short* vbase = vt + (size_t)(b * 1024 + h * 64 + w * 8 + srow8) * 2048 + gg * 8;
    // first K/V tile into buffer 0 (8 waves x 8 rows = 64 rows: 1 gload each)
    gload16(kbase + (size_t)kt0 * 3072, &Ks[0][(w * 8) * 64]);
    gload16(vbase + kt0,                &Vs[0][(w * 8) * 64]);

    // Q fragments straight from global (Q already log2e-scaled by the GEMM)
    bf16x8 qb[2];   // [ks]; wave owns q rows q0 + w*16 + l16
    {
        const unsigned short* qbase =
            qkv + (size_t)(b * S_LEN + q0 + w * 16 + l16) * 3072 + h * 64 + quad * 8;
        qb[0] = *(const bf16x8*)(qbase);
        qb[1] = *(const bf16x8*)(qbase + 32);
    }
    __syncthreads();   // bias_b + first K/V tile ready

    // ones-row A fragment for the row-sum MFMA: A[m=0][k]=1, rows 1..15 = 0.
    bf16x8 onesA = {};
    if (l16 == 0) {
        const __bf16 one = (__bf16)1.0f;
        for (int e = 0; e < 8; e++) onesA[e] = one;
    }

    f32x4 ctx[4] = {};       // ctx^T: [d-tile nd]
    f32x4 rsacc = {};        // row 0 (quad==0, reg 0) = running row sum per q
    const int ib0 = 127 + quad * 4 - w * 16 - l16;   // + i*64 + nb*16 + r

    int cur = 0;
    for (int i = 0; i < 16; i++) {
        // prefetch next K/V tile into the other buffer (latency hidden under compute)
        if (i < 15) {
            int ktn = kt0 + (i + 1) * 64;
            gload16(kbase + (size_t)ktn * 3072, &Ks[cur ^ 1][(w * 8) * 64]);
            gload16(vbase + ktn,                &Vs[cur ^ 1][(w * 8) * 64]);
        }
        // bias -> accumulator init (replaces zero-init AND the post-MFMA bias add)
        f32x4 st[4];
        const int ibt = ib0 + i * 64;
        for (int nb = 0; nb < 4; nb++) {
            const float* bp = &bias_b[ibt + nb * 16];
            st[nb][0] = bp[0]; st[nb][1] = bp[1];
            st[nb][2] = bp[2]; st[nb][3] = bp[3];
        }
        // S^T = K Q^T + bias : A = K rows (m=j), B = Q (n=q)
        __builtin_amdgcn_s_setprio(1);
        for (int ks = 0; ks < 2; ks++)
            for (int nb = 0; nb < 4; nb++) {
                bf16x8 ka = *(const bf16x8*)&Ks[cur][(nb * 16 + l16) * 64 + (((ks * 4 + quad) * 8) ^ swz)];
                st[nb] = __builtin_amdgcn_mfma_f32_16x16x32_bf16(ka, qb[ks], st[nb], 0, 0, 0);
            }
        __builtin_amdgcn_s_setprio(0);
        // exp2 softmax (scores already bias'd and log2e-scaled), pack to bf16 pairs
        uint2 pk[4];   // [nb]: P[j = nb*16+quad*4+{0..3}][q], packed
        for (int nb = 0; nb < 4; nb++) {
            float e0 = fexp2(st[nb][0]);
            float e1 = fexp2(st[nb][1]);
            float e2 = fexp2(st[nb][2]);
            float e3 = fexp2(st[nb][3]);
            pk[nb].x = pkbf(e0, e1);
            pk[nb].y = pkbf(e2, e3);
        }
        // in-register C-layout -> B-fragment remap (exchange among 4 lanes sharing l16):
        // permlane32_swap(X0,X1) -> (A,B); permlane16_swap(A,B) -> (dword0, dword2).
        // x-chain gives dwords {0,2}, y-chain gives dwords {1,3} of the bf16x8.
        __builtin_amdgcn_s_setprio(1);
        for (int ks = 0; ks < 2; ks++) {
            uint2 x0 = pk[2 * ks], x1 = pk[2 * ks + 1];
            auto sA = __builtin_amdgcn_permlane32_swap(x0.x, x1.x, false, false);
            auto sB = __builtin_amdgcn_permlane16_swap(sA[0], sA[1], false, false);
            auto sC = __builtin_amdgcn_permlane32_swap(x0.y, x1.y, false, false);
            auto sD = __builtin_amdgcn_permlane16_swap(sC[0], sC[1], false, false);
            unsigned int u4[4] = {sB[0], sD[0], sB[1], sD[1]};
            bf16x8 pbf;
            __builtin_memcpy(&pbf, u4, 16);
            rsacc = __builtin_amdgcn_mfma_f32_16x16x32_bf16(onesA, pbf, rsacc, 0, 0, 0);
            for (int nd = 0; nd < 4; nd++) {
                bf16x8 va = *(const bf16x8*)&Vs[cur][(nd * 16 + l16) * 64 + (((ks * 4 + quad) * 8) ^ swz)];
                ctx[nd] = __builtin_amdgcn_mfma_f32_16x16x32_bf16(va, pbf, ctx[nd], 0, 0, 0);
            }
        }
        __builtin_amdgcn_s_setprio(0);
        __syncthreads();   // drains prefetch vmcnt (already landed) + guards buffer swap
        cur ^= 1;
    }
    // epilogue: store UNNORMALIZED bf16 partials + fp32 row sums (row 0 of rsacc)
    unsigned short* cp = ctxpb + (size_t)ck * 4096 * 1024;
    {
        int row = b * S_LEN + q0 + w * 16 + l16;
        if (quad == 0) rsbuf[((size_t)ck * 4096 + row) * 16 + h] = rsacc[0];
        for (int nd = 0; nd < 4; nd++) {
            uint2 pk2;
            pk2.x = pkbf(ctx[nd][0], ctx[nd][1]);
            pk2.y = pkbf(ctx[nd][2], ctx[nd][3]);
            *(uint2*)&cp[(size_t)row * 1024 + h * 64 + nd * 16 + quad * 4] = pk2;
        }
    }
}

// ---------------- combine: ctx_bf16 = (ctx0 + ctx1) / (l0 + l1)
__global__ __launch_bounds__(256) void combine_kernel(const unsigned short* __restrict__ ctxpb,
                                                      const float* __restrict__ rsbuf,
                                                      unsigned short* __restrict__ ctxb){
    int e = blockIdx.x * 256 + threadIdx.x;     // one ushort4 per thread
    int row = e >> 8;
    int c4 = (e & 255) * 4;
    int h = c4 >> 6;
    float l = rsbuf[(size_t)row * 16 + h] + rsbuf[((size_t)4096 + row) * 16 + h];
    ushort4 a  = *(const ushort4*)&ctxpb[(size_t)row * 1024 + c4];
    ushort4 b2 = *(const ushort4*)&ctxpb[(size_t)4096 * 1024 + (size_t)row * 1024 + c4];
    float inv = 1.f / l;
    uint2 o;
    o.x = pkbf((bf2f(a.x) + bf2f(b2.x)) * inv, (bf2f(a.y) + bf2f(b2.y)) * inv);
    o.y = pkbf((bf2f(a.z) + bf2f(b2.z)) * inv, (bf2f(a.w) + bf2f(b2.w)) * inv);
    *(uint2*)&ctxb[(size_t)row * 1024 + c4] = o;
}

extern "C" void kernel_launch(void* const* d_in, const int* in_sizes, int n_in,
                              void* d_out, int out_size, void* d_ws, size_t ws_size,
                              hipStream_t stream) {
    const float* hs       = (const float*)d_in[0];
    const float* Wq       = (const float*)d_in[1];
    const float* Wk       = (const float*)d_in[2];
    const float* Wv       = (const float*)d_in[3];
    const float* Wo       = (const float*)d_in[4];
    const float* rel_bias = (const float*)d_in[5];
    float* out = (float*)d_out;

    char* ws = (char*)d_ws;
    float* biasT          = (float*)ws;           ws += 262144;      // 16*4095*4 (+pad)
    unsigned short* hsb   = (unsigned short*)ws;  ws += 8388608;     // 4096x1024 bf16
    unsigned short* WT    = (unsigned short*)ws;  ws += 6291456;     // [Wq^T|Wk^T|Wv^T] 3072x1024
    unsigned short* WoT   = (unsigned short*)ws;  ws += 2097152;     // 1024x1024 bf16
    unsigned short* qkvb  = (unsigned short*)ws;  ws += 25165824;    // 4096x3072 bf16 (Q|K|- )
    unsigned short* Vtg   = (unsigned short*)ws;  ws += 8388608;     // 2048x2048 bf16
    unsigned short* ctxb  = (unsigned short*)ws;  ws += 8388608;     // 4096x1024 bf16
    unsigned short* ctxpb = (unsigned short*)ws;  ws += 16777216;    // 2 x 4096x1024 bf16
    float* rsbuf          = (float*)ws;                              // 2 x 4096x16 fp32

    prep_kernel<<<dim3(32, 32, 5), 256, 0, stream>>>(
        hs, hsb, Wq, Wk, Wv, Wo,
        WT, WT + 1024 * 1024, WT + 2 * 1024 * 1024, WoT, rel_bias, biasT);

    // Q|K|V projection, BM=64 (1536 blocks = 6/CU; measured faster than BM=128 here)
    gemm_bt_kernel<1, 64><<<dim3(24, 64), 256, 0, stream>>>(hsb, WT, nullptr, qkvb, Vtg, 1024, 3072);
    // attention, split-S x2, q-tile 128: 1024 blocks = 4/CU, XCD-swizzled
    flash14_kernel<<<dim3(1024), 512, 0, stream>>>(qkvb, Vtg, biasT, ctxpb, rsbuf);
    // combine partials -> bf16 ctx
    combine_kernel<<<4096, 256, 0, stream>>>(ctxpb, rsbuf, ctxb);
    // output projection -> fp32 (BM=64: 512 blocks, 2/CU)
    gemm_bt_kernel<0, 64><<<dim3(8, 64), 256, 0, stream>>>(ctxb, WoT, out, nullptr, nullptr, 1024, 1024);
}

// Round 5
// 198.007 us; speedup vs baseline: 1.0361x; 1.0361x over previous
//
#include <hip/hip_runtime.h>
#include <hip/hip_bf16.h>
#include <stdint.h>

#define S_LEN 2048
#define NH 16
#define NB_DELTA (2*S_LEN-1)   // 4095
#define LOG2E 1.4426950408889634f

typedef __attribute__((ext_vector_type(8))) __bf16 bf16x8;
typedef __attribute__((ext_vector_type(4))) float f32x4;

__device__ __forceinline__ unsigned short f2bf(float f){   // RNE
    union { float f; unsigned int u; } v; v.f = f;
    unsigned int u = v.u;
    return (unsigned short)((u + 0x7FFFu + ((u >> 16) & 1u)) >> 16);
}
__device__ __forceinline__ float bf2f(unsigned short u){
    union { unsigned int u; float f; } v; v.u = ((unsigned int)u) << 16;
    return v.f;
}
__device__ __forceinline__ unsigned int pkbf(float a, float b){   // HW packed cvt (RNE)
    __hip_bfloat162 h = __float22bfloat162_rn(float2{a, b});
    unsigned int u;
    __builtin_memcpy(&u, &h, 4);
    return u;
}
#if __has_builtin(__builtin_amdgcn_exp2f)
__device__ __forceinline__ float fexp2(float x){ return __builtin_amdgcn_exp2f(x); }
#else
__device__ __forceinline__ float fexp2(float x){ return __expf(x * 0.69314718056f); }
#endif

// async global->LDS, 16B per lane; LDS dest = wave-uniform base + lane*16
__device__ __forceinline__ void gload16(const void* g, void* l){
    __builtin_amdgcn_global_load_lds(
        (const __attribute__((address_space(1))) void*)(uintptr_t)g,
        (__attribute__((address_space(3))) void*)(uintptr_t)l, 16, 0, 0);
}

// ---------------- fused prep: z<4 -> transpose+cast W[z]; z==4 -> hs cast + bias table
// biasT is PRE-SCALED: (bias - 16) * log2e  (exp2-softmax form; the -16 cancels in softmax)
__global__ __launch_bounds__(256) void prep_kernel(
    const float* __restrict__ hs, unsigned short* __restrict__ hsb,
    const float* __restrict__ W0, const float* __restrict__ W1,
    const float* __restrict__ W2, const float* __restrict__ W3,
    unsigned short* __restrict__ D0, unsigned short* __restrict__ D1,
    unsigned short* __restrict__ D2, unsigned short* __restrict__ D3,
    const float* __restrict__ rel_bias, float* __restrict__ biasT){
    if (blockIdx.z == 4) {
        int bi = blockIdx.y * 32 + blockIdx.x;   // 0..1023
        for (int it = 0; it < 4; it++) {
            int i = bi * 4096 + it * 1024 + threadIdx.x * 4;
            float4 f = *(const float4*)(hs + i);
            ushort4 o;
            o.x = f2bf(f.x); o.y = f2bf(f.y); o.z = f2bf(f.z); o.w = f2bf(f.w);
            *(ushort4*)(hsb + i) = o;
        }
        if (bi < 16) {
            int t = bi * 256 + threadIdx.x;
            if (t < NB_DELTA) {
                int delta = t - (S_LEN - 1);          // j - i
                int bucket = (delta > 0) ? 16 : 0;
                int a = delta < 0 ? -delta : delta;
                int b;
                if (a < 8) b = a;
                else {
                    int bl = 33 - __builtin_clz(a * a);   // 8 + floor(2*log2(a/8)), exact
                    b = bl < 15 ? bl : 15;
                }
                bucket += b;
                for (int h = 0; h < NH; h++)
                    biasT[h * NB_DELTA + t] = (rel_bias[bucket * NH + h] - 16.f) * LOG2E;
            }
        }
        return;
    }
    const float* src; unsigned short* dst;
    switch (blockIdx.z) {
        case 0: src = W0; dst = D0; break;
        case 1: src = W1; dst = D1; break;
        case 2: src = W2; dst = D2; break;
        default: src = W3; dst = D3; break;
    }
    __shared__ float tile[32][33];
    int bx = blockIdx.x, by = blockIdx.y;
    int tx = threadIdx.x & 31, ty = threadIdx.x >> 5;
    for (int i = 0; i < 4; i++)
        tile[ty + 8*i][tx] = src[(size_t)(by*32 + ty + 8*i) * 1024 + bx*32 + tx];
    __syncthreads();
    for (int i = 0; i < 4; i++)
        dst[(size_t)(bx*32 + ty + 8*i) * 1024 + by*32 + tx] = f2bf(tile[tx][ty + 8*i]);
}

// ---------------- bf16 MFMA GEMM, BK=64, async staging, XOR-granule-swizzled LDS.
// MODE 0: fp32 row-major into C0.
// MODE 1: bf16 row-major into C1 for cols<2048 (Q block pre-scaled by log2e);
//         cols>=2048 (the V block) are written TRANSPOSED into Vt[b*1024+v][s].
// MODE 2: like MODE 0, but A is the NORMALIZED context computed on the fly from
//         two bf16 partials (A, A+4096*1024) and row sums RS -- the combine
//         kernel fused into the A-staging (reg-stage + ds_write to the same
//         linear LDS slots gload16 would fill; identical rounding to combine).
template<int MODE, int BM>
__global__ __launch_bounds__(256) void gemm_bt_kernel(const unsigned short* __restrict__ A,
                                                      const unsigned short* __restrict__ BT,
                                                      float* __restrict__ C0,
                                                      unsigned short* __restrict__ C1,
                                                      unsigned short* __restrict__ Vt,
                                                      const float* __restrict__ RS,
                                                      int Kdim, int ldc){
    constexpr int IT = BM / 32;     // m-tiles per wave
    __shared__ __align__(16) unsigned short As[BM * 64];
    __shared__ __align__(16) unsigned short Bs[128 * 64];
    const int t = threadIdx.x;
    const int wave = t >> 6, lane = t & 63;
    const int quad = lane >> 4, l16 = lane & 15;
    const int wm = (wave >> 1) * (BM / 2), wn = (wave & 1) * 64;
    const size_t row0 = (size_t)blockIdx.y * BM, col0 = (size_t)blockIdx.x * 128;

    const int srow8 = lane >> 3;                 // 0..7: row within the wave's 8-row group
    const int gg = (lane & 7) ^ srow8;           // fetch-side granule remap
    const unsigned short* gA = A  + (row0 + wave * 8 + srow8) * (size_t)Kdim + gg * 8;
    const unsigned short* gB = BT + (col0 + wave * 8 + srow8) * (size_t)Kdim + gg * 8;

    f32x4 acc[IT][4] = {};

    for (int kt = 0; kt < Kdim; kt += 64) {
        if (MODE == 2) {
            // reg-stage normalized A from the two partials + row sums
            for (int p = 0; p < BM / 32; p++) {
                size_t row = row0 + p * 32 + wave * 8 + srow8;
                const unsigned short* pa = A + row * 1024 + kt + gg * 8;
                bf16x8 a0 = *(const bf16x8*)pa;
                bf16x8 a1 = *(const bf16x8*)(pa + (size_t)4096 * 1024);
                int head = kt >> 6;   // all 8 elems of this lane lie in one head
                float l = RS[row * 16 + head] + RS[(4096 + row) * 16 + head];
                float inv = 1.f / l;
                unsigned int u4[4];
                for (int e = 0; e < 4; e++) {
                    float x0 = (float)a0[2 * e]     + (float)a1[2 * e];
                    float x1 = (float)a0[2 * e + 1] + (float)a1[2 * e + 1];
                    u4[e] = pkbf(x0 * inv, x1 * inv);
                }
                bf16x8 pv;
                __builtin_memcpy(&pv, u4, 16);
                *(bf16x8*)&As[(p * 32 + wave * 8) * 64 + lane * 8] = pv;
            }
        } else {
            for (int p = 0; p < BM / 32; p++)
                gload16(gA + (size_t)(p * 32) * Kdim + kt, &As[(p * 32 + wave * 8) * 64]);
        }
        for (int p = 0; p < 4; p++)
            gload16(gB + (size_t)(p * 32) * Kdim + kt, &Bs[(p * 32 + wave * 8) * 64]);
        __syncthreads();
        bf16x8 a[2][IT], b[2][4];
        for (int ks = 0; ks < 2; ks++) {
            for (int i = 0; i < IT; i++)
                a[ks][i] = *(const bf16x8*)(&As[(wm + i*16 + l16) * 64 + (((ks*4 + quad) ^ (l16 & 7)) * 8)]);
            for (int j = 0; j < 4; j++)
                b[ks][j] = *(const bf16x8*)(&Bs[(wn + j*16 + l16) * 64 + (((ks*4 + quad) ^ (l16 & 7)) * 8)]);
        }
        for (int ks = 0; ks < 2; ks++)
            for (int i = 0; i < IT; i++)
                for (int j = 0; j < 4; j++)
                    acc[i][j] = __builtin_amdgcn_mfma_f32_16x16x32_bf16(a[ks][i], b[ks][j], acc[i][j], 0, 0, 0);
        __syncthreads();
    }
    // C/D layout: col = lane&15, row = quad*4 + reg
    for (int i = 0; i < IT; i++)
        for (int j = 0; j < 4; j++) {
            size_t r0 = row0 + wm + i*16 + quad*4;
            size_t c  = col0 + wn + j*16 + l16;
            if (MODE == 0 || MODE == 2) {
                for (int r = 0; r < 4; r++)
                    C0[(r0 + r) * ldc + c] = acc[i][j][r];
            } else if (c < 2048) {
                float qs = (c < 1024) ? LOG2E : 1.0f;   // pre-scale Q for exp2 softmax
                for (int r = 0; r < 4; r++)
                    C1[(r0 + r) * ldc + c] = f2bf(acc[i][j][r] * qs);
            } else {
                // V block: write transposed. rows r0..r0+3 are 4 consecutive s -> one 8B store.
                size_t bb = r0 >> 11, s = r0 & 2047;
                ushort4 o;
                o.x = f2bf(acc[i][j][0]); o.y = f2bf(acc[i][j][1]);
                o.z = f2bf(acc[i][j][2]); o.w = f2bf(acc[i][j][3]);
                *(ushort4*)(Vt + ((bb << 10) + (c - 2048)) * 2048 + s) = o;
            }
        }
}

// ---------------- MFMA flash attention v15 = v14 body with launch_bounds(512,4):
// v14's (512,8) forced a 32-VGPR allocation -> scratch spills (+19MB writes,
// per-iter L2 reloads). Natural allocation is ~60 VGPR <= 64, so HW reaches
// 8 waves/SIMD (4 blocks/CU, LDS 4x37.4=150<=160) WITHOUT coercion.
// Keeps: q-tile 128 (grid 1024 = 4/CU), chunked XCD swizzle, double-buffered
// K/V prefetch, bias as MFMA C-init, in-register P via permlane32/16_swap,
// row sums via ones-row MFMA.
__global__ __launch_bounds__(512, 4) void flash15_kernel(
    const unsigned short* __restrict__ qkv,
    const unsigned short* __restrict__ vt,
    const float* __restrict__ biasT,      // pre-scaled (x-16)*log2e
    unsigned short* __restrict__ ctxpb,   // [2][4096][1024] bf16 unnormalized
    float* __restrict__ rsbuf)            // [2][4096][16]  fp32 row sums
{
    // chunked XCD swizzle: physical lin -> logical id; the 16 blocks sharing
    // (h,b,ck) get identical lin%8 -> same XCD -> K/V panel fetched once/XCD.
    const int lin  = blockIdx.x;
    const int logi = (lin & 7) * 128 + (lin >> 3);
    const int qt = logi & 15, h = (logi >> 4) & 15;
    const int zz = logi >> 8;
    const int b = zz >> 1, ck = zz & 1;
    const int kt0 = ck << 10;
    const int t = threadIdx.x;
    const int w = t >> 6, lane = t & 63, quad = lane >> 4, l16 = lane & 15;
    const int q0 = qt * 128;

    __shared__ __align__(16) unsigned short Ks[2][64 * 64];   // [token j][dim], swizzled
    __shared__ __align__(16) unsigned short Vs[2][64 * 64];   // [dim d][token], swizzled
    __shared__ float bias_b[1152];                            // all deltas this block touches

    // bias table: delta range [kt0-q0-127, kt0-q0+1023] -> 1151 entries
    {
        const float* bsrc = biasT + h * NB_DELTA + (kt0 - q0 + 1920);   // 2047-127 = 1920
        for (int u = t; u < 1152; u += 512) bias_b[u] = bsrc[u];
    }
    const int srow8 = lane >> 3;
    const int gg = (lane & 7) ^ srow8;           // fetch-side granule remap
    const int swz = (l16 & 7) * 8;
    const unsigned short* kbase = qkv + (size_t)(b * S_LEN + w * 8 + srow8) * 3072 + 1024 + h * 64 + gg * 8;
    const unsigned short* vbase = vt + (size_t)(b * 1024 + h * 64 + w * 8 + srow8) * 2048 + gg * 8;
    // first K/V tile into buffer 0 (8 waves x 8 rows = 64 rows: 1 gload each)
    gload16(kbase + (size_t)kt0 * 3072, &Ks[0][(w * 8) * 64]);
    gload16(vbase + kt0,                &Vs[0][(w * 8) * 64]);

    // Q fragments straight from global (Q already log2e-scaled by the GEMM)
    bf16x8 qb[2];   // [ks]; wave owns q rows q0 + w*16 + l16
    {
        const unsigned short* qbase =
            qkv + (size_t)(b * S_LEN + q0 + w * 16 + l16) * 3072 + h * 64 + quad * 8;
        qb[0] = *(const bf16x8*)(qbase);
        qb[1] = *(const bf16x8*)(qbase + 32);
    }
    __syncthreads();   // bias_b + first K/V tile ready

    // ones-row A fragment for the row-sum MFMA: A[m=0][k]=1, rows 1..15 = 0.
    bf16x8 onesA = {};
    if (l16 == 0) {
        const __bf16 one = (__bf16)1.0f;
        for (int e = 0; e < 8; e++) onesA[e] = one;
    }

    f32x4 ctx[4] = {};       // ctx^T: [d-tile nd]
    f32x4 rsacc = {};        // row 0 (quad==0, reg 0) = running row sum per q
    const int ib0 = 127 + quad * 4 - w * 16 - l16;   // + i*64 + nb*16 + r

    int cur = 0;
    for (int i = 0; i < 16; i++) {
        // prefetch next K/V tile into the other buffer (latency hidden under compute)
        if (i < 15) {
            int ktn = kt0 + (i + 1) * 64;
            gload16(kbase + (size_t)ktn * 3072, &Ks[cur ^ 1][(w * 8) * 64]);
            gload16(vbase + ktn,                &Vs[cur ^ 1][(w * 8) * 64]);
        }
        // bias -> accumulator init (replaces zero-init AND the post-MFMA bias add)
        f32x4 st[4];
        const int ibt = ib0 + i * 64;
        for (int nb = 0; nb < 4; nb++) {
            const float* bp = &bias_b[ibt + nb * 16];
            st[nb][0] = bp[0]; st[nb][1] = bp[1];
            st[nb][2] = bp[2]; st[nb][3] = bp[3];
        }
        // S^T = K Q^T + bias : A = K rows (m=j), B = Q (n=q)
        __builtin_amdgcn_s_setprio(1);
        for (int ks = 0; ks < 2; ks++)
            for (int nb = 0; nb < 4; nb++) {
                bf16x8 ka = *(const bf16x8*)&Ks[cur][(nb * 16 + l16) * 64 + (((ks * 4 + quad) * 8) ^ swz)];
                st[nb] = __builtin_amdgcn_mfma_f32_16x16x32_bf16(ka, qb[ks], st[nb], 0, 0, 0);
            }
        __builtin_amdgcn_s_setprio(0);
        // exp2 softmax (scores already bias'd and log2e-scaled), pack to bf16 pairs
        uint2 pk[4];   // [nb]: P[j = nb*16+quad*4+{0..3}][q], packed
        for (int nb = 0; nb < 4; nb++) {
            float e0 = fexp2(st[nb][0]);
            float e1 = fexp2(st[nb][1]);
            float e2 = fexp2(st[nb][2]);
            float e3 = fexp2(st[nb][3]);
            pk[nb].x = pkbf(e0, e1);
            pk[nb].y = pkbf(e2, e3);
        }
        // in-register C-layout -> B-fragment remap (exchange among 4 lanes sharing l16):
        // permlane32_swap(X0,X1) -> (A,B); permlane16_swap(A,B) -> (dword0, dword2).
        // x-chain gives dwords {0,2}, y-chain gives dwords {1,3} of the bf16x8.
        __builtin_amdgcn_s_setprio(1);
        for (int ks = 0; ks < 2; ks++) {
            uint2 x0 = pk[2 * ks], x1 = pk[2 * ks + 1];
            auto sA = __builtin_amdgcn_permlane32_swap(x0.x, x1.x, false, false);
            auto sB = __builtin_amdgcn_permlane16_swap(sA[0], sA[1], false, false);
            auto sC = __builtin_amdgcn_permlane32_swap(x0.y, x1.y, false, false);
            auto sD = __builtin_amdgcn_permlane16_swap(sC[0], sC[1], false, false);
            unsigned int u4[4] = {sB[0], sD[0], sB[1], sD[1]};
            bf16x8 pbf;
            __builtin_memcpy(&pbf, u4, 16);
            rsacc = __builtin_amdgcn_mfma_f32_16x16x32_bf16(onesA, pbf, rsacc, 0, 0, 0);
            for (int nd = 0; nd < 4; nd++) {
                bf16x8 va = *(const bf16x8*)&Vs[cur][(nd * 16 + l16) * 64 + (((ks * 4 + quad) * 8) ^ swz)];
                ctx[nd] = __builtin_amdgcn_mfma_f32_16x16x32_bf16(va, pbf, ctx[nd], 0, 0, 0);
            }
        }
        __builtin_amdgcn_s_setprio(0);
        __syncthreads();   // drains prefetch vmcnt (already landed) + guards buffer swap
        cur ^= 1;
    }
    // epilogue: store UNNORMALIZED bf16 partials + fp32 row sums (row 0 of rsacc)
    unsigned short* cp = ctxpb + (size_t)ck * 4096 * 1024;
    {
        int row = b * S_LEN + q0 + w * 16 + l16;
        if (quad == 0) rsbuf[((size_t)ck * 4096 + row) * 16 + h] = rsacc[0];
        for (int nd = 0; nd < 4; nd++) {
            uint2 pk2;
            pk2.x = pkbf(ctx[nd][0], ctx[nd][1]);
            pk2.y = pkbf(ctx[nd][2], ctx[nd][3]);
            *(uint2*)&cp[(size_t)row * 1024 + h * 64 + nd * 16 + quad * 4] = pk2;
        }
    }
}

extern "C" void kernel_launch(void* const* d_in, const int* in_sizes, int n_in,
                              void* d_out, int out_size, void* d_ws, size_t ws_size,
                              hipStream_t stream) {
    const float* hs       = (const float*)d_in[0];
    const float* Wq       = (const float*)d_in[1];
    const float* Wk       = (const float*)d_in[2];
    const float* Wv       = (const float*)d_in[3];
    const float* Wo       = (const float*)d_in[4];
    const float* rel_bias = (const float*)d_in[5];
    float* out = (float*)d_out;

    char* ws = (char*)d_ws;
    float* biasT          = (float*)ws;           ws += 262144;      // 16*4095*4 (+pad)
    unsigned short* hsb   = (unsigned short*)ws;  ws += 8388608;     // 4096x1024 bf16
    unsigned short* WT    = (unsigned short*)ws;  ws += 6291456;     // [Wq^T|Wk^T|Wv^T] 3072x1024
    unsigned short* WoT   = (unsigned short*)ws;  ws += 2097152;     // 1024x1024 bf16
    unsigned short* qkvb  = (unsigned short*)ws;  ws += 25165824;    // 4096x3072 bf16 (Q|K|- )
    unsigned short* Vtg   = (unsigned short*)ws;  ws += 8388608;     // 2048x2048 bf16
    unsigned short* ctxb  = (unsigned short*)ws;  ws += 8388608;     // 4096x1024 bf16 (unused now)
    unsigned short* ctxpb = (unsigned short*)ws;  ws += 16777216;    // 2 x 4096x1024 bf16
    float* rsbuf          = (float*)ws;                              // 2 x 4096x16 fp32
    (void)ctxb;

    prep_kernel<<<dim3(32, 32, 5), 256, 0, stream>>>(
        hs, hsb, Wq, Wk, Wv, Wo,
        WT, WT + 1024 * 1024, WT + 2 * 1024 * 1024, WoT, rel_bias, biasT);

    // Q|K|V projection, BM=64 (1536 blocks = 6/CU; measured faster than BM=128 here)
    gemm_bt_kernel<1, 64><<<dim3(24, 64), 256, 0, stream>>>(hsb, WT, nullptr, qkvb, Vtg, nullptr, 1024, 3072);
    // attention, split-S x2, q-tile 128: 1024 blocks = 4/CU, XCD-swizzled
    flash15_kernel<<<dim3(1024), 512, 0, stream>>>(qkvb, Vtg, biasT, ctxpb, rsbuf);
    // output projection -> fp32, with combine (normalize partials) fused into A-staging
    gemm_bt_kernel<2, 64><<<dim3(8, 64), 256, 0, stream>>>(ctxpb, WoT, out, nullptr, nullptr, rsbuf, 1024, 1024);
}

// Round 6
// 194.523 us; speedup vs baseline: 1.0547x; 1.0179x over previous
//
#include <hip/hip_runtime.h>
#include <hip/hip_bf16.h>
#include <stdint.h>

#define S_LEN 2048
#define NH 16
#define NB_DELTA (2*S_LEN-1)   // 4095
#define LOG2E 1.4426950408889634f

typedef __attribute__((ext_vector_type(8))) __bf16 bf16x8;
typedef __attribute__((ext_vector_type(4))) float f32x4;

__device__ __forceinline__ unsigned short f2bf(float f){   // RNE
    union { float f; unsigned int u; } v; v.f = f;
    unsigned int u = v.u;
    return (unsigned short)((u + 0x7FFFu + ((u >> 16) & 1u)) >> 16);
}
__device__ __forceinline__ float bf2f(unsigned short u){
    union { unsigned int u; float f; } v; v.u = ((unsigned int)u) << 16;
    return v.f;
}
__device__ __forceinline__ unsigned int pkbf(float a, float b){   // HW packed cvt (RNE)
    __hip_bfloat162 h = __float22bfloat162_rn(float2{a, b});
    unsigned int u;
    __builtin_memcpy(&u, &h, 4);
    return u;
}
#if __has_builtin(__builtin_amdgcn_exp2f)
__device__ __forceinline__ float fexp2(float x){ return __builtin_amdgcn_exp2f(x); }
#else
__device__ __forceinline__ float fexp2(float x){ return __expf(x * 0.69314718056f); }
#endif

// async global->LDS, 16B per lane; LDS dest = wave-uniform base + lane*16
__device__ __forceinline__ void gload16(const void* g, void* l){
    __builtin_amdgcn_global_load_lds(
        (const __attribute__((address_space(1))) void*)(uintptr_t)g,
        (__attribute__((address_space(3))) void*)(uintptr_t)l, 16, 0, 0);
}

// ---------------- fused prep: z<4 -> transpose+cast W[z]; z==4 -> hs cast + bias table
// biasT is PRE-SCALED: (bias - 16) * log2e  (exp2-softmax form; the -16 cancels in softmax)
__global__ __launch_bounds__(256) void prep_kernel(
    const float* __restrict__ hs, unsigned short* __restrict__ hsb,
    const float* __restrict__ W0, const float* __restrict__ W1,
    const float* __restrict__ W2, const float* __restrict__ W3,
    unsigned short* __restrict__ D0, unsigned short* __restrict__ D1,
    unsigned short* __restrict__ D2, unsigned short* __restrict__ D3,
    const float* __restrict__ rel_bias, float* __restrict__ biasT){
    if (blockIdx.z == 4) {
        int bi = blockIdx.y * 32 + blockIdx.x;   // 0..1023
        for (int it = 0; it < 4; it++) {
            int i = bi * 4096 + it * 1024 + threadIdx.x * 4;
            float4 f = *(const float4*)(hs + i);
            ushort4 o;
            o.x = f2bf(f.x); o.y = f2bf(f.y); o.z = f2bf(f.z); o.w = f2bf(f.w);
            *(ushort4*)(hsb + i) = o;
        }
        if (bi < 16) {
            int t = bi * 256 + threadIdx.x;
            if (t < NB_DELTA) {
                int delta = t - (S_LEN - 1);          // j - i
                int bucket = (delta > 0) ? 16 : 0;
                int a = delta < 0 ? -delta : delta;
                int b;
                if (a < 8) b = a;
                else {
                    int bl = 33 - __builtin_clz(a * a);   // 8 + floor(2*log2(a/8)), exact
                    b = bl < 15 ? bl : 15;
                }
                bucket += b;
                for (int h = 0; h < NH; h++)
                    biasT[h * NB_DELTA + t] = (rel_bias[bucket * NH + h] - 16.f) * LOG2E;
            }
        }
        return;
    }
    const float* src; unsigned short* dst;
    switch (blockIdx.z) {
        case 0: src = W0; dst = D0; break;
        case 1: src = W1; dst = D1; break;
        case 2: src = W2; dst = D2; break;
        default: src = W3; dst = D3; break;
    }
    __shared__ float tile[32][33];
    int bx = blockIdx.x, by = blockIdx.y;
    int tx = threadIdx.x & 31, ty = threadIdx.x >> 5;
    for (int i = 0; i < 4; i++)
        tile[ty + 8*i][tx] = src[(size_t)(by*32 + ty + 8*i) * 1024 + bx*32 + tx];
    __syncthreads();
    for (int i = 0; i < 4; i++)
        dst[(size_t)(bx*32 + ty + 8*i) * 1024 + by*32 + tx] = f2bf(tile[tx][ty + 8*i]);
}

// ---------------- bf16 MFMA GEMM, BK=64, async staging, XOR-granule-swizzled LDS.
// MODE 0: fp32 row-major into C0 (ldc).
// MODE 1: bf16 into C1 with stride ldc for cols<2048 (Q block pre-scaled by
//         log2e; Q|K packed at stride 2048); cols>=2048 (the V block) are
//         written TRANSPOSED into Vt[b*1024+v][s].
template<int MODE, int BM>
__global__ __launch_bounds__(256) void gemm_bt_kernel(const unsigned short* __restrict__ A,
                                                      const unsigned short* __restrict__ BT,
                                                      float* __restrict__ C0,
                                                      unsigned short* __restrict__ C1,
                                                      unsigned short* __restrict__ Vt,
                                                      int Kdim, int ldc){
    constexpr int IT = BM / 32;     // m-tiles per wave
    __shared__ __align__(16) unsigned short As[BM * 64];
    __shared__ __align__(16) unsigned short Bs[128 * 64];
    const int t = threadIdx.x;
    const int wave = t >> 6, lane = t & 63;
    const int quad = lane >> 4, l16 = lane & 15;
    const int wm = (wave >> 1) * (BM / 2), wn = (wave & 1) * 64;
    const size_t row0 = (size_t)blockIdx.y * BM, col0 = (size_t)blockIdx.x * 128;

    const int srow8 = lane >> 3;                 // 0..7: row within the wave's 8-row group
    const int gg = (lane & 7) ^ srow8;           // fetch-side granule remap
    const unsigned short* gA = A  + (row0 + wave * 8 + srow8) * (size_t)Kdim + gg * 8;
    const unsigned short* gB = BT + (col0 + wave * 8 + srow8) * (size_t)Kdim + gg * 8;

    f32x4 acc[IT][4] = {};

    for (int kt = 0; kt < Kdim; kt += 64) {
        for (int p = 0; p < BM / 32; p++)
            gload16(gA + (size_t)(p * 32) * Kdim + kt, &As[(p * 32 + wave * 8) * 64]);
        for (int p = 0; p < 4; p++)
            gload16(gB + (size_t)(p * 32) * Kdim + kt, &Bs[(p * 32 + wave * 8) * 64]);
        __syncthreads();
        bf16x8 a[2][IT], b[2][4];
        for (int ks = 0; ks < 2; ks++) {
            for (int i = 0; i < IT; i++)
                a[ks][i] = *(const bf16x8*)(&As[(wm + i*16 + l16) * 64 + (((ks*4 + quad) ^ (l16 & 7)) * 8)]);
            for (int j = 0; j < 4; j++)
                b[ks][j] = *(const bf16x8*)(&Bs[(wn + j*16 + l16) * 64 + (((ks*4 + quad) ^ (l16 & 7)) * 8)]);
        }
        for (int ks = 0; ks < 2; ks++)
            for (int i = 0; i < IT; i++)
                for (int j = 0; j < 4; j++)
                    acc[i][j] = __builtin_amdgcn_mfma_f32_16x16x32_bf16(a[ks][i], b[ks][j], acc[i][j], 0, 0, 0);
        __syncthreads();
    }
    // C/D layout: col = lane&15, row = quad*4 + reg
    for (int i = 0; i < IT; i++)
        for (int j = 0; j < 4; j++) {
            size_t r0 = row0 + wm + i*16 + quad*4;
            size_t c  = col0 + wn + j*16 + l16;
            if (MODE == 0) {
                for (int r = 0; r < 4; r++)
                    C0[(r0 + r) * ldc + c] = acc[i][j][r];
            } else if (c < 2048) {
                float qs = (c < 1024) ? LOG2E : 1.0f;   // pre-scale Q for exp2 softmax
                for (int r = 0; r < 4; r++)
                    C1[(r0 + r) * ldc + c] = f2bf(acc[i][j][r] * qs);
            } else {
                // V block: write transposed. rows r0..r0+3 are 4 consecutive s -> one 8B store.
                size_t bb = r0 >> 11, s = r0 & 2047;
                ushort4 o;
                o.x = f2bf(acc[i][j][0]); o.y = f2bf(acc[i][j][1]);
                o.z = f2bf(acc[i][j][2]); o.w = f2bf(acc[i][j][3]);
                *(ushort4*)(Vt + ((bb << 10) + (c - 2048)) * 2048 + s) = o;
            }
        }
}

// ---------------- MFMA flash attention v16:
// v13's LDS-efficient wave shape (32 q/wave: each K/V LDS read amortized over
// 2x MFMA work) COMBINED with 4 blocks/CU: split-S x4 (512 j per block, 8
// k-tiles), grid 8qt x 16h x 2b x 4ck = 1024 blocks of 512 threads.
// LDS 35.8KB -> 4 blocks/CU (143KB). Chunked XCD swizzle keeps the 8
// qt-blocks sharing a K/V panel on one XCD.
// Keeps: double-buffered K/V prefetch, bias as MFMA C-init, in-register P via
// permlane32/16_swap, row sums via ones-row MFMA. Q|K input at stride 2048.
__global__ __launch_bounds__(512, 4) void flash16_kernel(
    const unsigned short* __restrict__ qkb,   // [4096][2048] bf16: Q | K
    const unsigned short* __restrict__ vt,    // [2][1024][2048] bf16 V^T
    const float* __restrict__ biasT,          // pre-scaled (x-16)*log2e
    unsigned short* __restrict__ ctxpb,       // [4][4096][1024] bf16 unnormalized
    float* __restrict__ rsbuf)                // [4][4096][16]  fp32 row sums
{
    // chunked XCD swizzle: the 8 qt-blocks sharing (h,b,ck) sit in one
    // 128-chunk -> one XCD -> K/V panel fetched once per XCD.
    const int lin  = blockIdx.x;
    const int logi = (lin & 7) * 128 + (lin >> 3);
    const int qt = logi & 7, h = (logi >> 3) & 15;
    const int zz = logi >> 7;                 // 0..7
    const int b = zz >> 2, ck = zz & 3;
    const int kt0 = ck << 9;                  // 512 j per chunk
    const int t = threadIdx.x;
    const int w = t >> 6, lane = t & 63, quad = lane >> 4, l16 = lane & 15;
    const int q0 = qt * 256;

    __shared__ __align__(16) unsigned short Ks[2][64 * 64];   // [token j][dim], swizzled
    __shared__ __align__(16) unsigned short Vs[2][64 * 64];   // [dim d][token], swizzled
    __shared__ float bias_b[768];                             // deltas this block touches

    // bias table: delta range [kt0-q0-255, kt0-q0+511] -> 767 entries
    {
        const float* bsrc = biasT + h * NB_DELTA + (kt0 - q0 + 1792);   // 2047-255 = 1792
        for (int u = t; u < 767; u += 512) bias_b[u] = bsrc[u];
    }
    const int srow8 = lane >> 3;
    const int gg = (lane & 7) ^ srow8;           // fetch-side granule remap
    const int swz = (l16 & 7) * 8;
    const unsigned short* kbase = qkb + (size_t)(b * S_LEN + w * 8 + srow8) * 2048 + 1024 + h * 64 + gg * 8;
    const unsigned short* vbase = vt + (size_t)(b * 1024 + h * 64 + w * 8 + srow8) * 2048 + gg * 8;
    // first K/V tile into buffer 0 (8 waves x 8 rows = 64 rows: 1 gload each)
    gload16(kbase + (size_t)kt0 * 2048, &Ks[0][(w * 8) * 64]);
    gload16(vbase + kt0,                &Vs[0][(w * 8) * 64]);

    // Q fragments straight from global (Q already log2e-scaled by the GEMM)
    bf16x8 qb[2][2];   // [ks][nt]; wave owns q rows q0 + w*32 + nt*16 + l16
    {
        const unsigned short* qbase =
            qkb + (size_t)(b * S_LEN + q0 + w * 32 + l16) * 2048 + h * 64 + quad * 8;
        for (int nt = 0; nt < 2; nt++)
            for (int ks = 0; ks < 2; ks++)
                qb[ks][nt] = *(const bf16x8*)(qbase + (size_t)nt * 16 * 2048 + ks * 32);
    }
    __syncthreads();   // bias_b + first K/V tile ready

    // ones-row A fragment for the row-sum MFMA: A[m=0][k]=1, rows 1..15 = 0.
    bf16x8 onesA = {};
    if (l16 == 0) {
        const __bf16 one = (__bf16)1.0f;
        for (int e = 0; e < 8; e++) onesA[e] = one;
    }

    f32x4 ctx[4][2] = {};    // ctx^T: [d-tile nd][n-tile nt]
    f32x4 rsacc[2] = {};     // row 0 (quad==0, reg 0) = running row sum per q
    const int ib0 = 255 + quad * 4 - w * 32 - l16;   // + i*64 - nt*16 + nb*16 + r

    int cur = 0;
    for (int i = 0; i < 8; i++) {
        // prefetch next K/V tile into the other buffer (latency hidden under compute)
        if (i < 7) {
            int ktn = kt0 + (i + 1) * 64;
            gload16(kbase + (size_t)ktn * 2048, &Ks[cur ^ 1][(w * 8) * 64]);
            gload16(vbase + ktn,                &Vs[cur ^ 1][(w * 8) * 64]);
        }
        // bias -> accumulator init (replaces zero-init AND the post-MFMA bias add)
        f32x4 st[4][2];
        const int ibt = ib0 + i * 64;
        for (int nt = 0; nt < 2; nt++)
            for (int nb = 0; nb < 4; nb++) {
                const float* bp = &bias_b[ibt - nt * 16 + nb * 16];
                st[nb][nt][0] = bp[0]; st[nb][nt][1] = bp[1];
                st[nb][nt][2] = bp[2]; st[nb][nt][3] = bp[3];
            }
        // S^T = K Q^T + bias : A = K rows (m=j), B = Q (n=q)
        __builtin_amdgcn_s_setprio(1);
        for (int ks = 0; ks < 2; ks++)
            for (int nb = 0; nb < 4; nb++) {
                bf16x8 ka = *(const bf16x8*)&Ks[cur][(nb * 16 + l16) * 64 + (((ks * 4 + quad) * 8) ^ swz)];
                st[nb][0] = __builtin_amdgcn_mfma_f32_16x16x32_bf16(ka, qb[ks][0], st[nb][0], 0, 0, 0);
                st[nb][1] = __builtin_amdgcn_mfma_f32_16x16x32_bf16(ka, qb[ks][1], st[nb][1], 0, 0, 0);
            }
        __builtin_amdgcn_s_setprio(0);
        // exp2 softmax (scores already bias'd and log2e-scaled), pack to bf16 pairs
        uint2 pk[2][4];   // [nt][nb]
        for (int nt = 0; nt < 2; nt++)
            for (int nb = 0; nb < 4; nb++) {
                float e0 = fexp2(st[nb][nt][0]);
                float e1 = fexp2(st[nb][nt][1]);
                float e2 = fexp2(st[nb][nt][2]);
                float e3 = fexp2(st[nb][nt][3]);
                pk[nt][nb].x = pkbf(e0, e1);
                pk[nt][nb].y = pkbf(e2, e3);
            }
        // in-register C-layout -> B-fragment remap (exchange among 4 lanes sharing l16)
        __builtin_amdgcn_s_setprio(1);
        for (int ks = 0; ks < 2; ks++) {
            bf16x8 pbf[2];
            for (int nt = 0; nt < 2; nt++) {
                uint2 x0 = pk[nt][2 * ks], x1 = pk[nt][2 * ks + 1];
                auto sA = __builtin_amdgcn_permlane32_swap(x0.x, x1.x, false, false);
                auto sB = __builtin_amdgcn_permlane16_swap(sA[0], sA[1], false, false);
                auto sC = __builtin_amdgcn_permlane32_swap(x0.y, x1.y, false, false);
                auto sD = __builtin_amdgcn_permlane16_swap(sC[0], sC[1], false, false);
                unsigned int u4[4] = {sB[0], sD[0], sB[1], sD[1]};
                __builtin_memcpy(&pbf[nt], u4, 16);
            }
            rsacc[0] = __builtin_amdgcn_mfma_f32_16x16x32_bf16(onesA, pbf[0], rsacc[0], 0, 0, 0);
            rsacc[1] = __builtin_amdgcn_mfma_f32_16x16x32_bf16(onesA, pbf[1], rsacc[1], 0, 0, 0);
            for (int nd = 0; nd < 4; nd++) {
                bf16x8 va = *(const bf16x8*)&Vs[cur][(nd * 16 + l16) * 64 + (((ks * 4 + quad) * 8) ^ swz)];
                ctx[nd][0] = __builtin_amdgcn_mfma_f32_16x16x32_bf16(va, pbf[0], ctx[nd][0], 0, 0, 0);
                ctx[nd][1] = __builtin_amdgcn_mfma_f32_16x16x32_bf16(va, pbf[1], ctx[nd][1], 0, 0, 0);
            }
        }
        __builtin_amdgcn_s_setprio(0);
        __syncthreads();   // drains prefetch vmcnt (already landed) + guards buffer swap
        cur ^= 1;
    }
    // epilogue: store UNNORMALIZED bf16 partials + fp32 row sums (row 0 of rsacc)
    unsigned short* cp = ctxpb + (size_t)ck * 4096 * 1024;
    for (int nt = 0; nt < 2; nt++) {
        int row = b * S_LEN + q0 + w * 32 + nt * 16 + l16;
        if (quad == 0) rsbuf[((size_t)ck * 4096 + row) * 16 + h] = rsacc[nt][0];
        for (int nd = 0; nd < 4; nd++) {
            uint2 pk2;
            pk2.x = pkbf(ctx[nd][nt][0], ctx[nd][nt][1]);
            pk2.y = pkbf(ctx[nd][nt][2], ctx[nd][nt][3]);
            *(uint2*)&cp[(size_t)row * 1024 + h * 64 + nd * 16 + quad * 4] = pk2;
        }
    }
}

// ---------------- combine: ctx_bf16 = (sum of 4 partials) / (sum of 4 row sums)
__global__ __launch_bounds__(256) void combine_kernel(const unsigned short* __restrict__ ctxpb,
                                                      const float* __restrict__ rsbuf,
                                                      unsigned short* __restrict__ ctxb){
    int e = blockIdx.x * 256 + threadIdx.x;     // one ushort4 per thread
    int row = e >> 8;
    int c4 = (e & 255) * 4;
    int h = c4 >> 6;
    float l = 0.f;
    for (int p = 0; p < 4; p++) l += rsbuf[((size_t)p * 4096 + row) * 16 + h];
    float s0 = 0.f, s1 = 0.f, s2 = 0.f, s3 = 0.f;
    for (int p = 0; p < 4; p++) {
        ushort4 a = *(const ushort4*)&ctxpb[(size_t)p * 4096 * 1024 + (size_t)row * 1024 + c4];
        s0 += bf2f(a.x); s1 += bf2f(a.y); s2 += bf2f(a.z); s3 += bf2f(a.w);
    }
    float inv = 1.f / l;
    uint2 o;
    o.x = pkbf(s0 * inv, s1 * inv);
    o.y = pkbf(s2 * inv, s3 * inv);
    *(uint2*)&ctxb[(size_t)row * 1024 + c4] = o;
}

extern "C" void kernel_launch(void* const* d_in, const int* in_sizes, int n_in,
                              void* d_out, int out_size, void* d_ws, size_t ws_size,
                              hipStream_t stream) {
    const float* hs       = (const float*)d_in[0];
    const float* Wq       = (const float*)d_in[1];
    const float* Wk       = (const float*)d_in[2];
    const float* Wv       = (const float*)d_in[3];
    const float* Wo       = (const float*)d_in[4];
    const float* rel_bias = (const float*)d_in[5];
    float* out = (float*)d_out;

    char* ws = (char*)d_ws;
    float* biasT          = (float*)ws;           ws += 262144;      // 16*4095*4 (+pad)
    unsigned short* hsb   = (unsigned short*)ws;  ws += 8388608;     // 4096x1024 bf16; DEAD after
                                                                     // gemm1 -> reused as ctxb
    unsigned short* WT    = (unsigned short*)ws;  ws += 6291456;     // [Wq^T|Wk^T|Wv^T] 3072x1024
    unsigned short* WoT   = (unsigned short*)ws;  ws += 2097152;     // 1024x1024 bf16
    unsigned short* qkb   = (unsigned short*)ws;  ws += 16777216;    // 4096x2048 bf16 (Q|K)
    unsigned short* Vtg   = (unsigned short*)ws;  ws += 8388608;     // 2048x2048 bf16
    unsigned short* ctxpb = (unsigned short*)ws;  ws += 33554432;    // 4 x 4096x1024 bf16
    float* rsbuf          = (float*)ws;                              // 4 x 4096x16 fp32
    unsigned short* ctxb  = hsb;                  // alias (hsb dead after gemm1)

    prep_kernel<<<dim3(32, 32, 5), 256, 0, stream>>>(
        hs, hsb, Wq, Wk, Wv, Wo,
        WT, WT + 1024 * 1024, WT + 2 * 1024 * 1024, WoT, rel_bias, biasT);

    // Q|K|V projection, BM=64 (1536 blocks = 6/CU); Q|K -> qkb (stride 2048), V -> Vtg
    gemm_bt_kernel<1, 64><<<dim3(24, 64), 256, 0, stream>>>(hsb, WT, nullptr, qkb, Vtg, 1024, 2048);
    // attention, split-S x4, 256-q blocks of 8 waves x 32q: 1024 blocks = 4/CU, XCD-swizzled
    flash16_kernel<<<dim3(1024), 512, 0, stream>>>(qkb, Vtg, biasT, ctxpb, rsbuf);
    // combine 4 partials -> bf16 ctx (into hsb's slot)
    combine_kernel<<<4096, 256, 0, stream>>>(ctxpb, rsbuf, ctxb);
    // output projection -> fp32 (BM=64: 512 blocks, 2/CU)
    gemm_bt_kernel<0, 64><<<dim3(8, 64), 256, 0, stream>>>(ctxb, WoT, out, nullptr, nullptr, 1024, 1024);
}

// Round 7
// 190.729 us; speedup vs baseline: 1.0756x; 1.0199x over previous
//
#include <hip/hip_runtime.h>
#include <hip/hip_bf16.h>
#include <stdint.h>

#define S_LEN 2048
#define NH 16
#define NB_DELTA (2*S_LEN-1)   // 4095
#define LOG2E 1.4426950408889634f

typedef __attribute__((ext_vector_type(8))) __bf16 bf16x8;
typedef __attribute__((ext_vector_type(4))) float f32x4;

__device__ __forceinline__ unsigned short f2bf(float f){   // RNE
    union { float f; unsigned int u; } v; v.f = f;
    unsigned int u = v.u;
    return (unsigned short)((u + 0x7FFFu + ((u >> 16) & 1u)) >> 16);
}
__device__ __forceinline__ float bf2f(unsigned short u){
    union { unsigned int u; float f; } v; v.u = ((unsigned int)u) << 16;
    return v.f;
}
__device__ __forceinline__ unsigned int pkbf(float a, float b){   // HW packed cvt (RNE)
    __hip_bfloat162 h = __float22bfloat162_rn(float2{a, b});
    unsigned int u;
    __builtin_memcpy(&u, &h, 4);
    return u;
}
#if __has_builtin(__builtin_amdgcn_exp2f)
__device__ __forceinline__ float fexp2(float x){ return __builtin_amdgcn_exp2f(x); }
#else
__device__ __forceinline__ float fexp2(float x){ return __expf(x * 0.69314718056f); }
#endif

// async global->LDS, 16B per lane; LDS dest = wave-uniform base + lane*16
__device__ __forceinline__ void gload16(const void* g, void* l){
    __builtin_amdgcn_global_load_lds(
        (const __attribute__((address_space(1))) void*)(uintptr_t)g,
        (__attribute__((address_space(3))) void*)(uintptr_t)l, 16, 0, 0);
}

// ---------------- fused prep: z<4 -> transpose+cast W[z]; z==4 -> hs cast + bias table
// biasT is PRE-SCALED: (bias - 16) * log2e  (exp2-softmax form; the -16 cancels in softmax)
__global__ __launch_bounds__(256) void prep_kernel(
    const float* __restrict__ hs, unsigned short* __restrict__ hsb,
    const float* __restrict__ W0, const float* __restrict__ W1,
    const float* __restrict__ W2, const float* __restrict__ W3,
    unsigned short* __restrict__ D0, unsigned short* __restrict__ D1,
    unsigned short* __restrict__ D2, unsigned short* __restrict__ D3,
    const float* __restrict__ rel_bias, float* __restrict__ biasT){
    if (blockIdx.z == 4) {
        int bi = blockIdx.y * 32 + blockIdx.x;   // 0..1023
        for (int it = 0; it < 4; it++) {
            int i = bi * 4096 + it * 1024 + threadIdx.x * 4;
            float4 f = *(const float4*)(hs + i);
            ushort4 o;
            o.x = f2bf(f.x); o.y = f2bf(f.y); o.z = f2bf(f.z); o.w = f2bf(f.w);
            *(ushort4*)(hsb + i) = o;
        }
        if (bi < 16) {
            int t = bi * 256 + threadIdx.x;
            if (t < NB_DELTA) {
                int delta = t - (S_LEN - 1);          // j - i
                int bucket = (delta > 0) ? 16 : 0;
                int a = delta < 0 ? -delta : delta;
                int b;
                if (a < 8) b = a;
                else {
                    int bl = 33 - __builtin_clz(a * a);   // 8 + floor(2*log2(a/8)), exact
                    b = bl < 15 ? bl : 15;
                }
                bucket += b;
                for (int h = 0; h < NH; h++)
                    biasT[h * NB_DELTA + t] = (rel_bias[bucket * NH + h] - 16.f) * LOG2E;
            }
        }
        return;
    }
    const float* src; unsigned short* dst;
    switch (blockIdx.z) {
        case 0: src = W0; dst = D0; break;
        case 1: src = W1; dst = D1; break;
        case 2: src = W2; dst = D2; break;
        default: src = W3; dst = D3; break;
    }
    __shared__ float tile[32][33];
    int bx = blockIdx.x, by = blockIdx.y;
    int tx = threadIdx.x & 31, ty = threadIdx.x >> 5;
    for (int i = 0; i < 4; i++)
        tile[ty + 8*i][tx] = src[(size_t)(by*32 + ty + 8*i) * 1024 + bx*32 + tx];
    __syncthreads();
    for (int i = 0; i < 4; i++)
        dst[(size_t)(bx*32 + ty + 8*i) * 1024 + by*32 + tx] = f2bf(tile[tx][ty + 8*i]);
}

// ---------------- bf16 MFMA GEMM, BK=64, async staging, XOR-granule-swizzled LDS.
// MODE 0: fp32 row-major into C0 (ldc).
// MODE 1: bf16 into C1 with stride ldc for cols<2048 (Q block pre-scaled by
//         log2e; Q|K packed at stride 2048); cols>=2048 (the V block) are
//         written TRANSPOSED into Vt[b*1024+v][s].
// MODE 2: like MODE 0, but A is the NORMALIZED context computed on the fly
//         from two bf16 partials (A, A+4096*1024) and row sums RS (combine
//         fused into A-staging). PREFETCHED: next K-step's partial loads are
//         issued before the barrier and consumed after the MFMA phase, so the
//         load latency hides under compute (fixes round-5's serial version).
template<int MODE, int BM>
__global__ __launch_bounds__(256) void gemm_bt_kernel(const unsigned short* __restrict__ A,
                                                      const unsigned short* __restrict__ BT,
                                                      float* __restrict__ C0,
                                                      unsigned short* __restrict__ C1,
                                                      unsigned short* __restrict__ Vt,
                                                      const float* __restrict__ RS,
                                                      int Kdim, int ldc){
    constexpr int IT = BM / 32;     // m-tiles per wave
    __shared__ __align__(16) unsigned short As[BM * 64];
    __shared__ __align__(16) unsigned short Bs[128 * 64];
    const int t = threadIdx.x;
    const int wave = t >> 6, lane = t & 63;
    const int quad = lane >> 4, l16 = lane & 15;
    const int wm = (wave >> 1) * (BM / 2), wn = (wave & 1) * 64;
    const size_t row0 = (size_t)blockIdx.y * BM, col0 = (size_t)blockIdx.x * 128;

    const int srow8 = lane >> 3;                 // 0..7: row within the wave's 8-row group
    const int gg = (lane & 7) ^ srow8;           // fetch-side granule remap
    const unsigned short* gA = A  + (row0 + wave * 8 + srow8) * (size_t)Kdim + gg * 8;
    const unsigned short* gB = BT + (col0 + wave * 8 + srow8) * (size_t)Kdim + gg * 8;

    f32x4 acc[IT][4] = {};

    // MODE 2 prefetch state (BM=64 -> 2 staged rows per thread)
    bf16x8 pa0[2], pa1[2];
    float ra[2], rb[2];
    auto issueA2 = [&](int kt){
        for (int p = 0; p < 2; p++) {
            size_t row = row0 + p * 32 + wave * 8 + srow8;
            const unsigned short* pp = A + row * 1024 + kt + gg * 8;
            pa0[p] = *(const bf16x8*)pp;
            pa1[p] = *(const bf16x8*)(pp + (size_t)4096 * 1024);
            int head = kt >> 6;
            ra[p] = RS[row * 16 + head];
            rb[p] = RS[(4096 + row) * 16 + head];
        }
    };
    if (MODE == 2) issueA2(0);

    for (int kt = 0; kt < Kdim; kt += 64) {
        if (MODE == 2) {
            // consume prefetched partials -> normalized bf16 -> LDS (linear slots)
            for (int p = 0; p < 2; p++) {
                float inv = 1.f / (ra[p] + rb[p]);
                unsigned int u4[4];
                for (int e = 0; e < 4; e++) {
                    float x0 = (float)pa0[p][2 * e]     + (float)pa1[p][2 * e];
                    float x1 = (float)pa0[p][2 * e + 1] + (float)pa1[p][2 * e + 1];
                    u4[e] = pkbf(x0 * inv, x1 * inv);
                }
                bf16x8 pv;
                __builtin_memcpy(&pv, u4, 16);
                *(bf16x8*)&As[(p * 32 + wave * 8) * 64 + lane * 8] = pv;
            }
        } else {
            for (int p = 0; p < BM / 32; p++)
                gload16(gA + (size_t)(p * 32) * Kdim + kt, &As[(p * 32 + wave * 8) * 64]);
        }
        for (int p = 0; p < 4; p++)
            gload16(gB + (size_t)(p * 32) * Kdim + kt, &Bs[(p * 32 + wave * 8) * 64]);
        if (MODE == 2 && kt + 64 < Kdim)
            issueA2(kt + 64);   // in flight across the MFMA phase + 2 barriers
        __syncthreads();
        bf16x8 a[2][IT], b[2][4];
        for (int ks = 0; ks < 2; ks++) {
            for (int i = 0; i < IT; i++)
                a[ks][i] = *(const bf16x8*)(&As[(wm + i*16 + l16) * 64 + (((ks*4 + quad) ^ (l16 & 7)) * 8)]);
            for (int j = 0; j < 4; j++)
                b[ks][j] = *(const bf16x8*)(&Bs[(wn + j*16 + l16) * 64 + (((ks*4 + quad) ^ (l16 & 7)) * 8)]);
        }
        for (int ks = 0; ks < 2; ks++)
            for (int i = 0; i < IT; i++)
                for (int j = 0; j < 4; j++)
                    acc[i][j] = __builtin_amdgcn_mfma_f32_16x16x32_bf16(a[ks][i], b[ks][j], acc[i][j], 0, 0, 0);
        __syncthreads();
    }
    // C/D layout: col = lane&15, row = quad*4 + reg
    for (int i = 0; i < IT; i++)
        for (int j = 0; j < 4; j++) {
            size_t r0 = row0 + wm + i*16 + quad*4;
            size_t c  = col0 + wn + j*16 + l16;
            if (MODE == 0 || MODE == 2) {
                for (int r = 0; r < 4; r++)
                    C0[(r0 + r) * ldc + c] = acc[i][j][r];
            } else if (c < 2048) {
                float qs = (c < 1024) ? LOG2E : 1.0f;   // pre-scale Q for exp2 softmax
                for (int r = 0; r < 4; r++)
                    C1[(r0 + r) * ldc + c] = f2bf(acc[i][j][r] * qs);
            } else {
                // V block: write transposed. rows r0..r0+3 are 4 consecutive s -> one 8B store.
                size_t bb = r0 >> 11, s = r0 & 2047;
                ushort4 o;
                o.x = f2bf(acc[i][j][0]); o.y = f2bf(acc[i][j][1]);
                o.z = f2bf(acc[i][j][2]); o.w = f2bf(acc[i][j][3]);
                *(ushort4*)(Vt + ((bb << 10) + (c - 2048)) * 2048 + s) = o;
            }
        }
}

// ---------------- MFMA flash attention v17 = v13 structure (best measured:
// split-S x2, 256-q blocks, 8 waves x 32q, 16 k-tiles, 2 blocks/CU) on the
// packed stride-2048 Q|K buffer, with chunked XCD swizzle.
// Keeps: double-buffered K/V prefetch, bias as MFMA C-init, in-register P via
// permlane32/16_swap, row sums via ones-row MFMA.
__global__ __launch_bounds__(512, 4) void flash17_kernel(
    const unsigned short* __restrict__ qkb,   // [4096][2048] bf16: Q | K
    const unsigned short* __restrict__ vt,    // [2][1024][2048] bf16 V^T
    const float* __restrict__ biasT,          // pre-scaled (x-16)*log2e
    unsigned short* __restrict__ ctxpb,       // [2][4096][1024] bf16 unnormalized
    float* __restrict__ rsbuf)                // [2][4096][16]  fp32 row sums
{
    // chunked XCD swizzle: the 8 qt-blocks sharing (h,b,ck) sit in one
    // 64-chunk -> one XCD -> K/V panel fetched once per XCD.
    const int lin  = blockIdx.x;               // 0..511
    const int logi = (lin & 7) * 64 + (lin >> 3);
    const int qt = logi & 7, h = (logi >> 3) & 15;
    const int zz = logi >> 7;                  // 0..3
    const int b = zz >> 1, ck = zz & 1;
    const int kt0 = ck << 10;                  // 1024 j per chunk
    const int t = threadIdx.x;
    const int w = t >> 6, lane = t & 63, quad = lane >> 4, l16 = lane & 15;
    const int q0 = qt * 256;

    __shared__ __align__(16) unsigned short Ks[2][64 * 64];   // [token j][dim], swizzled
    __shared__ __align__(16) unsigned short Vs[2][64 * 64];   // [dim d][token], swizzled
    __shared__ float bias_b[1280];                            // deltas this block touches

    // bias table: delta range [kt0-q0-255, kt0-q0+1023] -> 1279 entries
    {
        const float* bsrc = biasT + h * NB_DELTA + (kt0 - q0 + 1792);   // 2047-255 = 1792
        for (int u = t; u < 1279; u += 512) bias_b[u] = bsrc[u];
    }
    const int srow8 = lane >> 3;
    const int gg = (lane & 7) ^ srow8;           // fetch-side granule remap
    const int swz = (l16 & 7) * 8;
    const unsigned short* kbase = qkb + (size_t)(b * S_LEN + w * 8 + srow8) * 2048 + 1024 + h * 64 + gg * 8;
    const unsigned short* vbase = vt + (size_t)(b * 1024 + h * 64 + w * 8 + srow8) * 2048 + gg * 8;
    // first K/V tile into buffer 0 (8 waves x 8 rows = 64 rows: 1 gload each)
    gload16(kbase + (size_t)kt0 * 2048, &Ks[0][(w * 8) * 64]);
    gload16(vbase + kt0,                &Vs[0][(w * 8) * 64]);

    // Q fragments straight from global (Q already log2e-scaled by the GEMM)
    bf16x8 qb[2][2];   // [ks][nt]; wave owns q rows q0 + w*32 + nt*16 + l16
    {
        const unsigned short* qbase =
            qkb + (size_t)(b * S_LEN + q0 + w * 32 + l16) * 2048 + h * 64 + quad * 8;
        for (int nt = 0; nt < 2; nt++)
            for (int ks = 0; ks < 2; ks++)
                qb[ks][nt] = *(const bf16x8*)(qbase + (size_t)nt * 16 * 2048 + ks * 32);
    }
    __syncthreads();   // bias_b + first K/V tile ready

    // ones-row A fragment for the row-sum MFMA: A[m=0][k]=1, rows 1..15 = 0.
    bf16x8 onesA = {};
    if (l16 == 0) {
        const __bf16 one = (__bf16)1.0f;
        for (int e = 0; e < 8; e++) onesA[e] = one;
    }

    f32x4 ctx[4][2] = {};    // ctx^T: [d-tile nd][n-tile nt]
    f32x4 rsacc[2] = {};     // row 0 (quad==0, reg 0) = running row sum per q
    const int ib0 = 255 + quad * 4 - w * 32 - l16;   // + i*64 - nt*16 + nb*16 + r

    int cur = 0;
    for (int i = 0; i < 16; i++) {
        // prefetch next K/V tile into the other buffer (latency hidden under compute)
        if (i < 15) {
            int ktn = kt0 + (i + 1) * 64;
            gload16(kbase + (size_t)ktn * 2048, &Ks[cur ^ 1][(w * 8) * 64]);
            gload16(vbase + ktn,                &Vs[cur ^ 1][(w * 8) * 64]);
        }
        // bias -> accumulator init (replaces zero-init AND the post-MFMA bias add)
        f32x4 st[4][2];
        const int ibt = ib0 + i * 64;
        for (int nt = 0; nt < 2; nt++)
            for (int nb = 0; nb < 4; nb++) {
                const float* bp = &bias_b[ibt - nt * 16 + nb * 16];
                st[nb][nt][0] = bp[0]; st[nb][nt][1] = bp[1];
                st[nb][nt][2] = bp[2]; st[nb][nt][3] = bp[3];
            }
        // S^T = K Q^T + bias : A = K rows (m=j), B = Q (n=q)
        __builtin_amdgcn_s_setprio(1);
        for (int ks = 0; ks < 2; ks++)
            for (int nb = 0; nb < 4; nb++) {
                bf16x8 ka = *(const bf16x8*)&Ks[cur][(nb * 16 + l16) * 64 + (((ks * 4 + quad) * 8) ^ swz)];
                st[nb][0] = __builtin_amdgcn_mfma_f32_16x16x32_bf16(ka, qb[ks][0], st[nb][0], 0, 0, 0);
                st[nb][1] = __builtin_amdgcn_mfma_f32_16x16x32_bf16(ka, qb[ks][1], st[nb][1], 0, 0, 0);
            }
        __builtin_amdgcn_s_setprio(0);
        // exp2 softmax (scores already bias'd and log2e-scaled), pack to bf16 pairs
        uint2 pk[2][4];   // [nt][nb]
        for (int nt = 0; nt < 2; nt++)
            for (int nb = 0; nb < 4; nb++) {
                float e0 = fexp2(st[nb][nt][0]);
                float e1 = fexp2(st[nb][nt][1]);
                float e2 = fexp2(st[nb][nt][2]);
                float e3 = fexp2(st[nb][nt][3]);
                pk[nt][nb].x = pkbf(e0, e1);
                pk[nt][nb].y = pkbf(e2, e3);
            }
        // in-register C-layout -> B-fragment remap (exchange among 4 lanes sharing l16)
        __builtin_amdgcn_s_setprio(1);
        for (int ks = 0; ks < 2; ks++) {
            bf16x8 pbf[2];
            for (int nt = 0; nt < 2; nt++) {
                uint2 x0 = pk[nt][2 * ks], x1 = pk[nt][2 * ks + 1];
                auto sA = __builtin_amdgcn_permlane32_swap(x0.x, x1.x, false, false);
                auto sB = __builtin_amdgcn_permlane16_swap(sA[0], sA[1], false, false);
                auto sC = __builtin_amdgcn_permlane32_swap(x0.y, x1.y, false, false);
                auto sD = __builtin_amdgcn_permlane16_swap(sC[0], sC[1], false, false);
                unsigned int u4[4] = {sB[0], sD[0], sB[1], sD[1]};
                __builtin_memcpy(&pbf[nt], u4, 16);
            }
            rsacc[0] = __builtin_amdgcn_mfma_f32_16x16x32_bf16(onesA, pbf[0], rsacc[0], 0, 0, 0);
            rsacc[1] = __builtin_amdgcn_mfma_f32_16x16x32_bf16(onesA, pbf[1], rsacc[1], 0, 0, 0);
            for (int nd = 0; nd < 4; nd++) {
                bf16x8 va = *(const bf16x8*)&Vs[cur][(nd * 16 + l16) * 64 + (((ks * 4 + quad) * 8) ^ swz)];
                ctx[nd][0] = __builtin_amdgcn_mfma_f32_16x16x32_bf16(va, pbf[0], ctx[nd][0], 0, 0, 0);
                ctx[nd][1] = __builtin_amdgcn_mfma_f32_16x16x32_bf16(va, pbf[1], ctx[nd][1], 0, 0, 0);
            }
        }
        __builtin_amdgcn_s_setprio(0);
        __syncthreads();   // drains prefetch vmcnt (already landed) + guards buffer swap
        cur ^= 1;
    }
    // epilogue: store UNNORMALIZED bf16 partials + fp32 row sums (row 0 of rsacc)
    unsigned short* cp = ctxpb + (size_t)ck * 4096 * 1024;
    for (int nt = 0; nt < 2; nt++) {
        int row = b * S_LEN + q0 + w * 32 + nt * 16 + l16;
        if (quad == 0) rsbuf[((size_t)ck * 4096 + row) * 16 + h] = rsacc[nt][0];
        for (int nd = 0; nd < 4; nd++) {
            uint2 pk2;
            pk2.x = pkbf(ctx[nd][nt][0], ctx[nd][nt][1]);
            pk2.y = pkbf(ctx[nd][nt][2], ctx[nd][nt][3]);
            *(uint2*)&cp[(size_t)row * 1024 + h * 64 + nd * 16 + quad * 4] = pk2;
        }
    }
}

extern "C" void kernel_launch(void* const* d_in, const int* in_sizes, int n_in,
                              void* d_out, int out_size, void* d_ws, size_t ws_size,
                              hipStream_t stream) {
    const float* hs       = (const float*)d_in[0];
    const float* Wq       = (const float*)d_in[1];
    const float* Wk       = (const float*)d_in[2];
    const float* Wv       = (const float*)d_in[3];
    const float* Wo       = (const float*)d_in[4];
    const float* rel_bias = (const float*)d_in[5];
    float* out = (float*)d_out;

    char* ws = (char*)d_ws;
    float* biasT          = (float*)ws;           ws += 262144;      // 16*4095*4 (+pad)
    unsigned short* hsb   = (unsigned short*)ws;  ws += 8388608;     // 4096x1024 bf16
    unsigned short* WT    = (unsigned short*)ws;  ws += 6291456;     // [Wq^T|Wk^T|Wv^T] 3072x1024
    unsigned short* WoT   = (unsigned short*)ws;  ws += 2097152;     // 1024x1024 bf16
    unsigned short* qkb   = (unsigned short*)ws;  ws += 16777216;    // 4096x2048 bf16 (Q|K)
    unsigned short* Vtg   = (unsigned short*)ws;  ws += 8388608;     // 2048x2048 bf16
    unsigned short* ctxpb = (unsigned short*)ws;  ws += 16777216;    // 2 x 4096x1024 bf16
    float* rsbuf          = (float*)ws;                              // 2 x 4096x16 fp32

    prep_kernel<<<dim3(32, 32, 5), 256, 0, stream>>>(
        hs, hsb, Wq, Wk, Wv, Wo,
        WT, WT + 1024 * 1024, WT + 2 * 1024 * 1024, WoT, rel_bias, biasT);

    // Q|K|V projection, BM=64 (1536 blocks = 6/CU); Q|K -> qkb (stride 2048), V -> Vtg
    gemm_bt_kernel<1, 64><<<dim3(24, 64), 256, 0, stream>>>(hsb, WT, nullptr, qkb, Vtg, nullptr, 1024, 2048);
    // attention, split-S x2, 256-q blocks of 8 waves x 32q: 512 blocks = 2/CU, XCD-swizzled
    flash17_kernel<<<dim3(512), 512, 0, stream>>>(qkb, Vtg, biasT, ctxpb, rsbuf);
    // output projection -> fp32, with combine fused into PREFETCHED A-staging
    gemm_bt_kernel<2, 64><<<dim3(8, 64), 256, 0, stream>>>(ctxpb, WoT, out, nullptr, nullptr, rsbuf, 1024, 1024);
}

// Round 8
// 189.868 us; speedup vs baseline: 1.0805x; 1.0045x over previous
//
#include <hip/hip_runtime.h>
#include <hip/hip_bf16.h>
#include <stdint.h>

#define S_LEN 2048
#define NH 16
#define NB_DELTA (2*S_LEN-1)   // 4095
#define LOG2E 1.4426950408889634f

typedef __attribute__((ext_vector_type(8))) __bf16 bf16x8;
typedef __attribute__((ext_vector_type(4))) float f32x4;

__device__ __forceinline__ unsigned short f2bf(float f){   // RNE
    union { float f; unsigned int u; } v; v.f = f;
    unsigned int u = v.u;
    return (unsigned short)((u + 0x7FFFu + ((u >> 16) & 1u)) >> 16);
}
__device__ __forceinline__ float bf2f(unsigned short u){
    union { unsigned int u; float f; } v; v.u = ((unsigned int)u) << 16;
    return v.f;
}
__device__ __forceinline__ unsigned int pkbf(float a, float b){   // HW packed cvt (RNE)
    __hip_bfloat162 h = __float22bfloat162_rn(float2{a, b});
    unsigned int u;
    __builtin_memcpy(&u, &h, 4);
    return u;
}
#if __has_builtin(__builtin_amdgcn_exp2f)
__device__ __forceinline__ float fexp2(float x){ return __builtin_amdgcn_exp2f(x); }
#else
__device__ __forceinline__ float fexp2(float x){ return __expf(x * 0.69314718056f); }
#endif

// async global->LDS, 16B per lane; LDS dest = wave-uniform base + lane*16
__device__ __forceinline__ void gload16(const void* g, void* l){
    __builtin_amdgcn_global_load_lds(
        (const __attribute__((address_space(1))) void*)(uintptr_t)g,
        (__attribute__((address_space(3))) void*)(uintptr_t)l, 16, 0, 0);
}

// ---------------- fused prep: z<4 -> transpose+cast W[z]; z==4 -> hs cast + bias table
// biasT is PRE-SCALED: (bias - 16) * log2e  (exp2-softmax form; the -16 cancels in softmax)
__global__ __launch_bounds__(256) void prep_kernel(
    const float* __restrict__ hs, unsigned short* __restrict__ hsb,
    const float* __restrict__ W0, const float* __restrict__ W1,
    const float* __restrict__ W2, const float* __restrict__ W3,
    unsigned short* __restrict__ D0, unsigned short* __restrict__ D1,
    unsigned short* __restrict__ D2, unsigned short* __restrict__ D3,
    const float* __restrict__ rel_bias, float* __restrict__ biasT){
    if (blockIdx.z == 4) {
        int bi = blockIdx.y * 32 + blockIdx.x;   // 0..1023
        for (int it = 0; it < 4; it++) {
            int i = bi * 4096 + it * 1024 + threadIdx.x * 4;
            float4 f = *(const float4*)(hs + i);
            ushort4 o;
            o.x = f2bf(f.x); o.y = f2bf(f.y); o.z = f2bf(f.z); o.w = f2bf(f.w);
            *(ushort4*)(hsb + i) = o;
        }
        if (bi < 16) {
            int t = bi * 256 + threadIdx.x;
            if (t < NB_DELTA) {
                int delta = t - (S_LEN - 1);          // j - i
                int bucket = (delta > 0) ? 16 : 0;
                int a = delta < 0 ? -delta : delta;
                int b;
                if (a < 8) b = a;
                else {
                    int bl = 33 - __builtin_clz(a * a);   // 8 + floor(2*log2(a/8)), exact
                    b = bl < 15 ? bl : 15;
                }
                bucket += b;
                for (int h = 0; h < NH; h++)
                    biasT[h * NB_DELTA + t] = (rel_bias[bucket * NH + h] - 16.f) * LOG2E;
            }
        }
        return;
    }
    const float* src; unsigned short* dst;
    switch (blockIdx.z) {
        case 0: src = W0; dst = D0; break;
        case 1: src = W1; dst = D1; break;
        case 2: src = W2; dst = D2; break;
        default: src = W3; dst = D3; break;
    }
    __shared__ float tile[32][33];
    int bx = blockIdx.x, by = blockIdx.y;
    int tx = threadIdx.x & 31, ty = threadIdx.x >> 5;
    for (int i = 0; i < 4; i++)
        tile[ty + 8*i][tx] = src[(size_t)(by*32 + ty + 8*i) * 1024 + bx*32 + tx];
    __syncthreads();
    for (int i = 0; i < 4; i++)
        dst[(size_t)(bx*32 + ty + 8*i) * 1024 + by*32 + tx] = f2bf(tile[tx][ty + 8*i]);
}

// ---------------- bf16 MFMA GEMM, BK=64, async staging, XOR-granule-swizzled LDS.
// MODE 0: fp32 row-major into C0 (ldc).
// MODE 1: bf16 into C1 with stride ldc for cols<2048 (Q block pre-scaled by
//         log2e; Q|K packed at stride 2048); cols>=2048 (the V block) are
//         written TRANSPOSED into Vt[b*1024+v][s].
// MODE 2: like MODE 0, but A is the NORMALIZED context computed on the fly
//         from two bf16 partials (A, A+4096*1024) and row sums RS (combine
//         fused into A-staging), with 1-step register prefetch.
template<int MODE, int BM>
__global__ __launch_bounds__(256) void gemm_bt_kernel(const unsigned short* __restrict__ A,
                                                      const unsigned short* __restrict__ BT,
                                                      float* __restrict__ C0,
                                                      unsigned short* __restrict__ C1,
                                                      unsigned short* __restrict__ Vt,
                                                      const float* __restrict__ RS,
                                                      int Kdim, int ldc){
    constexpr int IT = BM / 32;     // m-tiles per wave
    __shared__ __align__(16) unsigned short As[BM * 64];
    __shared__ __align__(16) unsigned short Bs[128 * 64];
    const int t = threadIdx.x;
    const int wave = t >> 6, lane = t & 63;
    const int quad = lane >> 4, l16 = lane & 15;
    const int wm = (wave >> 1) * (BM / 2), wn = (wave & 1) * 64;
    const size_t row0 = (size_t)blockIdx.y * BM, col0 = (size_t)blockIdx.x * 128;

    const int srow8 = lane >> 3;                 // 0..7: row within the wave's 8-row group
    const int gg = (lane & 7) ^ srow8;           // fetch-side granule remap
    const unsigned short* gA = A  + (row0 + wave * 8 + srow8) * (size_t)Kdim + gg * 8;
    const unsigned short* gB = BT + (col0 + wave * 8 + srow8) * (size_t)Kdim + gg * 8;

    f32x4 acc[IT][4] = {};

    // MODE 2 prefetch state (BM=64 -> 2 staged rows per thread)
    bf16x8 pa0[2], pa1[2];
    float ra[2], rb[2];
    auto issueA2 = [&](int kt){
        for (int p = 0; p < 2; p++) {
            size_t row = row0 + p * 32 + wave * 8 + srow8;
            const unsigned short* pp = A + row * 1024 + kt + gg * 8;
            pa0[p] = *(const bf16x8*)pp;
            pa1[p] = *(const bf16x8*)(pp + (size_t)4096 * 1024);
            int head = kt >> 6;
            ra[p] = RS[row * 16 + head];
            rb[p] = RS[(4096 + row) * 16 + head];
        }
    };
    if (MODE == 2) issueA2(0);

    for (int kt = 0; kt < Kdim; kt += 64) {
        if (MODE == 2) {
            // consume prefetched partials -> normalized bf16 -> LDS (linear slots)
            for (int p = 0; p < 2; p++) {
                float inv = 1.f / (ra[p] + rb[p]);
                unsigned int u4[4];
                for (int e = 0; e < 4; e++) {
                    float x0 = (float)pa0[p][2 * e]     + (float)pa1[p][2 * e];
                    float x1 = (float)pa0[p][2 * e + 1] + (float)pa1[p][2 * e + 1];
                    u4[e] = pkbf(x0 * inv, x1 * inv);
                }
                bf16x8 pv;
                __builtin_memcpy(&pv, u4, 16);
                *(bf16x8*)&As[(p * 32 + wave * 8) * 64 + lane * 8] = pv;
            }
        } else {
            for (int p = 0; p < BM / 32; p++)
                gload16(gA + (size_t)(p * 32) * Kdim + kt, &As[(p * 32 + wave * 8) * 64]);
        }
        for (int p = 0; p < 4; p++)
            gload16(gB + (size_t)(p * 32) * Kdim + kt, &Bs[(p * 32 + wave * 8) * 64]);
        if (MODE == 2 && kt + 64 < Kdim)
            issueA2(kt + 64);   // in flight across the MFMA phase + 2 barriers
        __syncthreads();
        bf16x8 a[2][IT], b[2][4];
        for (int ks = 0; ks < 2; ks++) {
            for (int i = 0; i < IT; i++)
                a[ks][i] = *(const bf16x8*)(&As[(wm + i*16 + l16) * 64 + (((ks*4 + quad) ^ (l16 & 7)) * 8)]);
            for (int j = 0; j < 4; j++)
                b[ks][j] = *(const bf16x8*)(&Bs[(wn + j*16 + l16) * 64 + (((ks*4 + quad) ^ (l16 & 7)) * 8)]);
        }
        for (int ks = 0; ks < 2; ks++)
            for (int i = 0; i < IT; i++)
                for (int j = 0; j < 4; j++)
                    acc[i][j] = __builtin_amdgcn_mfma_f32_16x16x32_bf16(a[ks][i], b[ks][j], acc[i][j], 0, 0, 0);
        __syncthreads();
    }
    // C/D layout: col = lane&15, row = quad*4 + reg
    for (int i = 0; i < IT; i++)
        for (int j = 0; j < 4; j++) {
            size_t r0 = row0 + wm + i*16 + quad*4;
            size_t c  = col0 + wn + j*16 + l16;
            if (MODE == 0 || MODE == 2) {
                for (int r = 0; r < 4; r++)
                    C0[(r0 + r) * ldc + c] = acc[i][j][r];
            } else if (c < 2048) {
                float qs = (c < 1024) ? LOG2E : 1.0f;   // pre-scale Q for exp2 softmax
                for (int r = 0; r < 4; r++)
                    C1[(r0 + r) * ldc + c] = f2bf(acc[i][j][r] * qs);
            } else {
                // V block: write transposed. rows r0..r0+3 are 4 consecutive s -> one 8B store.
                size_t bb = r0 >> 11, s = r0 & 2047;
                ushort4 o;
                o.x = f2bf(acc[i][j][0]); o.y = f2bf(acc[i][j][1]);
                o.z = f2bf(acc[i][j][2]); o.w = f2bf(acc[i][j][3]);
                *(ushort4*)(Vt + ((bb << 10) + (c - 2048)) * 2048 + s) = o;
            }
        }
}

// ---------------- MFMA flash attention v18 = v17 with:
// (a) nb-outer SOFTWARE-PIPELINED QK^T: each st[nb] completes after its own 4
//     chained MFMAs, so its 8 exp2 + 2 cvt_pk issue while nb+1..3's MFMAs are
//     in flight (breaks the serial QK->exp->PV phase chain; no barrier between).
// (b) 16B-aligned float4 bias table bias4_b (20KB LDS): bias C-init is 2
//     ds_read_b128 per nb instead of 8 unaligned ds_read_b32 + addr VALU.
// Keeps: split-S x2, 8 waves x 32q, chunked XCD swizzle, double-buffered K/V
// prefetch, in-register P via permlane32/16_swap, row sums via ones-row MFMA.
__global__ __launch_bounds__(512, 4) void flash18_kernel(
    const unsigned short* __restrict__ qkb,   // [4096][2048] bf16: Q | K
    const unsigned short* __restrict__ vt,    // [2][1024][2048] bf16 V^T
    const float* __restrict__ biasT,          // pre-scaled (x-16)*log2e
    unsigned short* __restrict__ ctxpb,       // [2][4096][1024] bf16 unnormalized
    float* __restrict__ rsbuf)                // [2][4096][16]  fp32 row sums
{
    // chunked XCD swizzle: the 8 qt-blocks sharing (h,b,ck) sit in one
    // 64-chunk -> one XCD -> K/V panel fetched once per XCD.
    const int lin  = blockIdx.x;               // 0..511
    const int logi = (lin & 7) * 64 + (lin >> 3);
    const int qt = logi & 7, h = (logi >> 3) & 15;
    const int zz = logi >> 7;                  // 0..3
    const int b = zz >> 1, ck = zz & 1;
    const int kt0 = ck << 10;                  // 1024 j per chunk
    const int t = threadIdx.x;
    const int w = t >> 6, lane = t & 63, quad = lane >> 4, l16 = lane & 15;
    const int q0 = qt * 256;

    __shared__ __align__(16) unsigned short Ks[2][64 * 64];   // [token j][dim], swizzled
    __shared__ __align__(16) unsigned short Vs[2][64 * 64];   // [dim d][token], swizzled
    __shared__ __align__(16) float bias4_b[1280 * 4];         // redundant x4: entry u = biasT[u..u+3]

    // bias table: delta range [kt0-q0-255, kt0-q0+1023]; max used entry 1275
    {
        const float* bsrc = biasT + h * NB_DELTA + (kt0 - q0 + 1792);   // 2047-255 = 1792
        for (int u = t; u < 1276; u += 512) {
            float a0 = bsrc[u], a1 = bsrc[u + 1], a2 = bsrc[u + 2], a3 = bsrc[u + 3];
            float4* d = (float4*)&bias4_b[u * 4];
            *d = float4{a0, a1, a2, a3};
        }
    }
    const int srow8 = lane >> 3;
    const int gg = (lane & 7) ^ srow8;           // fetch-side granule remap
    const int swz = (l16 & 7) * 8;
    const unsigned short* kbase = qkb + (size_t)(b * S_LEN + w * 8 + srow8) * 2048 + 1024 + h * 64 + gg * 8;
    const unsigned short* vbase = vt + (size_t)(b * 1024 + h * 64 + w * 8 + srow8) * 2048 + gg * 8;
    // first K/V tile into buffer 0 (8 waves x 8 rows = 64 rows: 1 gload each)
    gload16(kbase + (size_t)kt0 * 2048, &Ks[0][(w * 8) * 64]);
    gload16(vbase + kt0,                &Vs[0][(w * 8) * 64]);

    // Q fragments straight from global (Q already log2e-scaled by the GEMM)
    bf16x8 qb[2][2];   // [ks][nt]; wave owns q rows q0 + w*32 + nt*16 + l16
    {
        const unsigned short* qbase =
            qkb + (size_t)(b * S_LEN + q0 + w * 32 + l16) * 2048 + h * 64 + quad * 8;
        for (int nt = 0; nt < 2; nt++)
            for (int ks = 0; ks < 2; ks++)
                qb[ks][nt] = *(const bf16x8*)(qbase + (size_t)nt * 16 * 2048 + ks * 32);
    }
    __syncthreads();   // bias4_b + first K/V tile ready

    // ones-row A fragment for the row-sum MFMA: A[m=0][k]=1, rows 1..15 = 0.
    bf16x8 onesA = {};
    if (l16 == 0) {
        const __bf16 one = (__bf16)1.0f;
        for (int e = 0; e < 8; e++) onesA[e] = one;
    }

    f32x4 ctx[4][2] = {};    // ctx^T: [d-tile nd][n-tile nt]
    f32x4 rsacc[2] = {};     // row 0 (quad==0, reg 0) = running row sum per q
    const int ib0 = 255 + quad * 4 - w * 32 - l16;   // + i*64 - nt*16 + nb*16 + r

    int cur = 0;
    for (int i = 0; i < 16; i++) {
        // prefetch next K/V tile into the other buffer (latency hidden under compute)
        if (i < 15) {
            int ktn = kt0 + (i + 1) * 64;
            gload16(kbase + (size_t)ktn * 2048, &Ks[cur ^ 1][(w * 8) * 64]);
            gload16(vbase + ktn,                &Vs[cur ^ 1][(w * 8) * 64]);
        }
        // nb-outer pipelined QK^T + softmax: st[nb] = K_nb Q^T + bias (C-init),
        // its exp2/cvt_pk overlap nb+1's MFMAs (no barrier in between).
        const int ibt = ib0 + i * 64;
        uint2 pk[2][4];   // [nt][nb]
        for (int nb = 0; nb < 4; nb++) {
            const int krow = (nb * 16 + l16) * 64;
            bf16x8 ka0 = *(const bf16x8*)&Ks[cur][krow + ((quad * 8) ^ swz)];
            bf16x8 ka1 = *(const bf16x8*)&Ks[cur][krow + (((4 + quad) * 8) ^ swz)];
            f32x4 st0 = *(const f32x4*)&bias4_b[(ibt + nb * 16) * 4];        // nt=0
            f32x4 st1 = *(const f32x4*)&bias4_b[(ibt - 16 + nb * 16) * 4];   // nt=1
            st0 = __builtin_amdgcn_mfma_f32_16x16x32_bf16(ka0, qb[0][0], st0, 0, 0, 0);
            st0 = __builtin_amdgcn_mfma_f32_16x16x32_bf16(ka1, qb[1][0], st0, 0, 0, 0);
            st1 = __builtin_amdgcn_mfma_f32_16x16x32_bf16(ka0, qb[0][1], st1, 0, 0, 0);
            st1 = __builtin_amdgcn_mfma_f32_16x16x32_bf16(ka1, qb[1][1], st1, 0, 0, 0);
            pk[0][nb].x = pkbf(fexp2(st0[0]), fexp2(st0[1]));
            pk[0][nb].y = pkbf(fexp2(st0[2]), fexp2(st0[3]));
            pk[1][nb].x = pkbf(fexp2(st1[0]), fexp2(st1[1]));
            pk[1][nb].y = pkbf(fexp2(st1[2]), fexp2(st1[3]));
        }
        // in-register C-layout -> B-fragment remap (exchange among 4 lanes sharing l16)
        __builtin_amdgcn_s_setprio(1);
        for (int ks = 0; ks < 2; ks++) {
            bf16x8 pbf[2];
            for (int nt = 0; nt < 2; nt++) {
                uint2 x0 = pk[nt][2 * ks], x1 = pk[nt][2 * ks + 1];
                auto sA = __builtin_amdgcn_permlane32_swap(x0.x, x1.x, false, false);
                auto sB = __builtin_amdgcn_permlane16_swap(sA[0], sA[1], false, false);
                auto sC = __builtin_amdgcn_permlane32_swap(x0.y, x1.y, false, false);
                auto sD = __builtin_amdgcn_permlane16_swap(sC[0], sC[1], false, false);
                unsigned int u4[4] = {sB[0], sD[0], sB[1], sD[1]};
                __builtin_memcpy(&pbf[nt], u4, 16);
            }
            rsacc[0] = __builtin_amdgcn_mfma_f32_16x16x32_bf16(onesA, pbf[0], rsacc[0], 0, 0, 0);
            rsacc[1] = __builtin_amdgcn_mfma_f32_16x16x32_bf16(onesA, pbf[1], rsacc[1], 0, 0, 0);
            for (int nd = 0; nd < 4; nd++) {
                bf16x8 va = *(const bf16x8*)&Vs[cur][(nd * 16 + l16) * 64 + (((ks * 4 + quad) * 8) ^ swz)];
                ctx[nd][0] = __builtin_amdgcn_mfma_f32_16x16x32_bf16(va, pbf[0], ctx[nd][0], 0, 0, 0);
                ctx[nd][1] = __builtin_amdgcn_mfma_f32_16x16x32_bf16(va, pbf[1], ctx[nd][1], 0, 0, 0);
            }
        }
        __builtin_amdgcn_s_setprio(0);
        __syncthreads();   // drains prefetch vmcnt (already landed) + guards buffer swap
        cur ^= 1;
    }
    // epilogue: store UNNORMALIZED bf16 partials + fp32 row sums (row 0 of rsacc)
    unsigned short* cp = ctxpb + (size_t)ck * 4096 * 1024;
    for (int nt = 0; nt < 2; nt++) {
        int row = b * S_LEN + q0 + w * 32 + nt * 16 + l16;
        if (quad == 0) rsbuf[((size_t)ck * 4096 + row) * 16 + h] = rsacc[nt][0];
        for (int nd = 0; nd < 4; nd++) {
            uint2 pk2;
            pk2.x = pkbf(ctx[nd][nt][0], ctx[nd][nt][1]);
            pk2.y = pkbf(ctx[nd][nt][2], ctx[nd][nt][3]);
            *(uint2*)&cp[(size_t)row * 1024 + h * 64 + nd * 16 + quad * 4] = pk2;
        }
    }
}

extern "C" void kernel_launch(void* const* d_in, const int* in_sizes, int n_in,
                              void* d_out, int out_size, void* d_ws, size_t ws_size,
                              hipStream_t stream) {
    const float* hs       = (const float*)d_in[0];
    const float* Wq       = (const float*)d_in[1];
    const float* Wk       = (const float*)d_in[2];
    const float* Wv       = (const float*)d_in[3];
    const float* Wo       = (const float*)d_in[4];
    const float* rel_bias = (const float*)d_in[5];
    float* out = (float*)d_out;

    char* ws = (char*)d_ws;
    float* biasT          = (float*)ws;           ws += 262144;      // 16*4095*4 (+pad)
    unsigned short* hsb   = (unsigned short*)ws;  ws += 8388608;     // 4096x1024 bf16
    unsigned short* WT    = (unsigned short*)ws;  ws += 6291456;     // [Wq^T|Wk^T|Wv^T] 3072x1024
    unsigned short* WoT   = (unsigned short*)ws;  ws += 2097152;     // 1024x1024 bf16
    unsigned short* qkb   = (unsigned short*)ws;  ws += 16777216;    // 4096x2048 bf16 (Q|K)
    unsigned short* Vtg   = (unsigned short*)ws;  ws += 8388608;     // 2048x2048 bf16
    unsigned short* ctxpb = (unsigned short*)ws;  ws += 16777216;    // 2 x 4096x1024 bf16
    float* rsbuf          = (float*)ws;                              // 2 x 4096x16 fp32

    prep_kernel<<<dim3(32, 32, 5), 256, 0, stream>>>(
        hs, hsb, Wq, Wk, Wv, Wo,
        WT, WT + 1024 * 1024, WT + 2 * 1024 * 1024, WoT, rel_bias, biasT);

    // Q|K|V projection, BM=64 (1536 blocks = 6/CU); Q|K -> qkb (stride 2048), V -> Vtg
    gemm_bt_kernel<1, 64><<<dim3(24, 64), 256, 0, stream>>>(hsb, WT, nullptr, qkb, Vtg, nullptr, 1024, 2048);
    // attention, split-S x2, 256-q blocks of 8 waves x 32q: 512 blocks = 2/CU, XCD-swizzled
    flash18_kernel<<<dim3(512), 512, 0, stream>>>(qkb, Vtg, biasT, ctxpb, rsbuf);
    // output projection -> fp32, with combine fused into PREFETCHED A-staging
    gemm_bt_kernel<2, 64><<<dim3(8, 64), 256, 0, stream>>>(ctxpb, WoT, out, nullptr, nullptr, rsbuf, 1024, 1024);
}